// Round 2
// 984.353 us; speedup vs baseline: 1.1007x; 1.1007x over previous
//
#include <hip/hip_runtime.h>

// ---------------------------------------------------------------------------
// Problem constants
// ---------------------------------------------------------------------------
#define NUSER 50000
#define NITEM 50000
#define NEDGE 100000
#define HDIM  512      // H*D
#define KIN   256      // input feature dim

typedef unsigned short ushort_t;
typedef __attribute__((ext_vector_type(8))) short short8;
typedef __attribute__((ext_vector_type(4))) float f32x4;

static __device__ __forceinline__ float bf2f(ushort_t u) {
    unsigned v = ((unsigned)u) << 16;
    float f;
    __builtin_memcpy(&f, &v, 4);
    return f;
}
static __device__ __forceinline__ ushort_t f2bf(float f) {
    unsigned u;
    __builtin_memcpy(&u, &f, 4);
    unsigned r = u + 0x7fffu + ((u >> 16) & 1u);  // RNE
    return (ushort_t)(r >> 16);
}
// runtime-dtype scalar load
static __device__ __forceinline__ float ldf(const void* p, long i, bool fp32) {
    return fp32 ? ((const float*)p)[i] : bf2f(((const ushort_t*)p)[i]);
}

static __device__ __forceinline__ short8 pack_bf8(float4 a, float4 b) {
    short8 r;
    r[0] = (short)f2bf(a.x); r[1] = (short)f2bf(a.y);
    r[2] = (short)f2bf(a.z); r[3] = (short)f2bf(a.w);
    r[4] = (short)f2bf(b.x); r[5] = (short)f2bf(b.y);
    r[6] = (short)f2bf(b.z); r[7] = (short)f2bf(b.w);
    return r;
}

// ---------------------------------------------------------------------------
// D0: runtime dtype detection (0 = bf16, 1 = fp32). fp32 read as bf16 gives
// huge decoded values w.p. ~1 over 4096 samples; bf16 N(0,1) maxes ~4.
// ---------------------------------------------------------------------------
__global__ void detect_kernel(const ushort_t* __restrict__ x, int* __restrict__ flag) {
    __shared__ float red[256];
    int tid = threadIdx.x;
    float m = 0.f;
    for (int i = tid; i < 4096; i += 256) m = fmaxf(m, fabsf(bf2f(x[i])));
    red[tid] = m;
    __syncthreads();
    for (int s = 128; s > 0; s >>= 1) {
        if (tid < s) red[tid] = fmaxf(red[tid], red[tid + s]);
        __syncthreads();
    }
    if (tid == 0) *flag = (red[0] > 1e6f) ? 1 : 0;
}

// ---------------------------------------------------------------------------
// P0: effective attention weights, one block per head (grid = 8).
// weff[h][k] = 0.125 * sum_d wa[d]*W[h*64+d][k];  beff[h] = 0.125 * wa.b[h]
// ---------------------------------------------------------------------------
__global__ void eff_w_kernel(const void* __restrict__ W,   // 512x256
                             const void* __restrict__ b,   // 512
                             const void* __restrict__ wa,  // 64
                             float* __restrict__ weff,     // 8x256
                             float* __restrict__ beff,     // 8
                             const int* __restrict__ flag) {
    bool fp32 = (*flag != 0);
    int h = blockIdx.x;      // 0..7
    int k = threadIdx.x;     // 0..255
    __shared__ float was[64];
    __shared__ float red[64];
    if (k < 64) was[k] = ldf(wa, k, fp32);
    __syncthreads();
    float s = 0.f;
#pragma unroll 8
    for (int d = 0; d < 64; d++)
        s += was[d] * ldf(W, (long)(h * 64 + d) * KIN + k, fp32);
    weff[h * KIN + k] = 0.125f * s;
    if (k < 64) red[k] = was[k] * ldf(b, h * 64 + k, fp32);
    __syncthreads();
    if (k == 0) {
        float t = 0.f;
        for (int d = 0; d < 64; d++) t += red[d];
        beff[h] = 0.125f * t;
    }
}

// ---------------------------------------------------------------------------
// P1: per-node attention scalars aq[n][h], ak[n][h] (pre-scaled by 1/8)
// block 256 = 4 waves, one node per wave. grid = N/4
// ---------------------------------------------------------------------------
__global__ void attn_scalar_kernel(const void* __restrict__ X,     // N x 256
                                   const float* __restrict__ weff, // 16 x 256 (q:0-7, k:8-15)
                                   const float* __restrict__ beff, // 16
                                   float* __restrict__ aq,         // N x 8
                                   float* __restrict__ ak,         // N x 8
                                   const int* __restrict__ flag) {
    __shared__ float wl[16 * KIN];
    int tid = threadIdx.x;
    for (int i = tid; i < 16 * KIN; i += 256) wl[i] = weff[i];
    bool fp32 = (*flag != 0);
    __syncthreads();
    int lane = tid & 63, w = tid >> 6;
    int n = blockIdx.x * 4 + w;
    float xv0, xv1, xv2, xv3;
    if (fp32) {
        const float* xr = (const float*)X + (size_t)n * KIN + lane * 4;
        float4 u = *(const float4*)xr;
        xv0 = u.x; xv1 = u.y; xv2 = u.z; xv3 = u.w;
    } else {
        const ushort_t* xr = (const ushort_t*)X + (size_t)n * KIN + lane * 4;
        uint2 u = *(const uint2*)xr;
        xv0 = bf2f(u.x & 0xffff); xv1 = bf2f(u.x >> 16);
        xv2 = bf2f(u.y & 0xffff); xv3 = bf2f(u.y >> 16);
    }
    float p[16];
#pragma unroll
    for (int o = 0; o < 16; o++) {
        float4 wv = *(const float4*)&wl[o * KIN + lane * 4];
        p[o] = xv0 * wv.x + xv1 * wv.y + xv2 * wv.z + xv3 * wv.w;
    }
#pragma unroll
    for (int o = 0; o < 16; o++) {
        float v = p[o];
#pragma unroll
        for (int m = 32; m > 0; m >>= 1) v += __shfl_xor(v, m);
        if (lane == o) {
            float r = v + beff[o];
            if (o < 8) aq[n * 8 + o] = r;
            else       ak[n * 8 + (o - 8)] = r;
        }
    }
}

// ---------------------------------------------------------------------------
// P2: v projection GEMM, stateless fragment-in-register design.
// M=50000, N=512, K=256. Block = 4 waves = 256 threads.
// blockIdx.x = rc*2 + cg: rc = 128-row chunk, cg = 256-col group.
// Wave w owns a 64-col strip: its B fragments (4 nf x 8 ks short8 = 128 VGPR)
// are loaded+converted ONCE from the original W layout, then the wave streams
// 4 row-tiles of 32 rows, loading A directly from global (coalesced 32B/lane)
// and issuing 8 MFMA per A-load pair. No LDS, no barriers, no staging buffer,
// no extra workspace: reads only inputs, writes only C. K-accumulation order
// (ks = 0..7 of 32) is identical to the previous passing version.
// ---------------------------------------------------------------------------
__global__ __launch_bounds__(256, 2) void gemm_v3_kernel(
        const void* __restrict__ A, const void* __restrict__ W,
        const void* __restrict__ bias, ushort_t* __restrict__ C, int M,
        const int* __restrict__ flag) {
    bool fp32 = (*flag != 0);
    int tid = threadIdx.x;
    int lane = tid & 63, w = tid >> 6;
    int rc = blockIdx.x >> 1;            // row chunk (128 rows)
    int cg = blockIdx.x & 1;             // column group (256 cols)
    int nf0 = cg * 16 + w * 4;           // first 16-col fragment of this wave
    int colb = lane & 15;
    int kl = (lane >> 4) * 8;            // k-offset within a 32-slice

    // --- B fragments, converted once into registers: breg[nf][ks] ---
    short8 breg[4][8];
#pragma unroll
    for (int nf = 0; nf < 4; nf++) {
        int col = (nf0 + nf) * 16 + colb;    // W row index (= output column)
#pragma unroll
        for (int ks = 0; ks < 8; ks++) {
            int k0 = ks * 32 + kl;
            if (fp32) {
                const float* p = (const float*)W + (size_t)col * KIN + k0;
                breg[nf][ks] = pack_bf8(*(const float4*)p, *(const float4*)(p + 4));
            } else {
                breg[nf][ks] = *(const short8*)((const ushort_t*)W + (size_t)col * KIN + k0);
            }
        }
    }
    float bv[4];
#pragma unroll
    for (int nf = 0; nf < 4; nf++)
        bv[nf] = ldf(bias, (nf0 + nf) * 16 + colb, fp32);

    int rq = lane >> 4;
    for (int rt = 0; rt < 4; rt++) {
        int row0 = rc * 128 + rt * 32;
        if (row0 >= M) break;
        int r0 = row0 + colb, r1 = r0 + 16;
        if (r0 > M - 1) r0 = M - 1;      // clamp loads; stores are guarded
        if (r1 > M - 1) r1 = M - 1;
        f32x4 acc[2][4] = {};
#pragma unroll
        for (int ks = 0; ks < 8; ks++) {
            short8 a0, a1;
            if (fp32) {
                const float* p0 = (const float*)A + (size_t)r0 * KIN + ks * 32 + kl;
                const float* p1 = (const float*)A + (size_t)r1 * KIN + ks * 32 + kl;
                a0 = pack_bf8(*(const float4*)p0, *(const float4*)(p0 + 4));
                a1 = pack_bf8(*(const float4*)p1, *(const float4*)(p1 + 4));
            } else {
                a0 = *(const short8*)((const ushort_t*)A + (size_t)r0 * KIN + ks * 32 + kl);
                a1 = *(const short8*)((const ushort_t*)A + (size_t)r1 * KIN + ks * 32 + kl);
            }
#pragma unroll
            for (int nf = 0; nf < 4; nf++) {
                acc[0][nf] = __builtin_amdgcn_mfma_f32_16x16x32_bf16(a0, breg[nf][ks], acc[0][nf], 0, 0, 0);
                acc[1][nf] = __builtin_amdgcn_mfma_f32_16x16x32_bf16(a1, breg[nf][ks], acc[1][nf], 0, 0, 0);
            }
        }
#pragma unroll
        for (int mi = 0; mi < 2; mi++) {
#pragma unroll
            for (int r = 0; r < 4; r++) {
                int row = row0 + mi * 16 + rq * 4 + r;
                if (row < M) {
                    ushort_t* crow = C + (size_t)row * HDIM;
#pragma unroll
                    for (int nf = 0; nf < 4; nf++)
                        crow[(nf0 + nf) * 16 + colb] = f2bf(acc[mi][nf][r] + bv[nf]);
                }
            }
        }
    }
}

// ---------------------------------------------------------------------------
// E1: per-edge exp weights + denominator + degree
// ---------------------------------------------------------------------------
__global__ void edge_pass1_kernel(const int* __restrict__ src, const int* __restrict__ dst,
                                  const float* __restrict__ ak,   // src-ntype, N x 8
                                  const float* __restrict__ aq,   // dst-ntype, N x 8
                                  float* __restrict__ wbuf,       // E x 8
                                  float* __restrict__ den,        // Nd x 8 (zeroed)
                                  int* __restrict__ deg) {        // Nd (zeroed)
    int e = blockIdx.x * 256 + threadIdx.x;
    if (e >= NEDGE) return;
    int s = src[e], d = dst[e];
#pragma unroll
    for (int h = 0; h < 8; h++) {
        float sc = ak[s * 8 + h] + aq[d * 8 + h];
        float wv = __expf(sc);
        wbuf[e * 8 + h] = wv;
        atomicAdd(&den[d * 8 + h], wv);
    }
    atomicAdd(&deg[d], 1);
}

// ---------------------------------------------------------------------------
// Scan: exclusive prefix sum of deg -> offs, 3 edge types, one launch
// ---------------------------------------------------------------------------
__global__ void scan3_kernel(const int* __restrict__ deg0, const int* __restrict__ deg1,
                             const int* __restrict__ deg2, int* __restrict__ offs0,
                             int* __restrict__ offs1, int* __restrict__ offs2) {
    const int Nd = NUSER;
    const int* deg = blockIdx.x == 0 ? deg0 : (blockIdx.x == 1 ? deg1 : deg2);
    int* offs = blockIdx.x == 0 ? offs0 : (blockIdx.x == 1 ? offs1 : offs2);
    __shared__ int lds[1024];
    int tid = threadIdx.x;
    int chunk = (Nd + 1023) >> 10;
    int s = tid * chunk;
    int e = s + chunk; if (e > Nd) e = Nd;
    int local = 0;
    for (int i = s; i < e; i++) local += deg[i];
    lds[tid] = local;
    __syncthreads();
    for (int d = 1; d < 1024; d <<= 1) {
        int v = (tid >= d) ? lds[tid - d] : 0;
        __syncthreads();
        lds[tid] += v;
        __syncthreads();
    }
    int run = (tid > 0) ? lds[tid - 1] : 0;
    for (int i = s; i < e; i++) { offs[i] = run; run += deg[i]; }
}

// ---------------------------------------------------------------------------
// E2: scatter edge ids into dst-sorted order
// ---------------------------------------------------------------------------
__global__ void edge_scatter_kernel(const int* __restrict__ dst, const int* __restrict__ offs,
                                    int* __restrict__ cur, int* __restrict__ esort) {
    int e = blockIdx.x * 256 + threadIdx.x;
    if (e >= NEDGE) return;
    int d = dst[e];
    int p = offs[d] + atomicAdd(&cur[d], 1);
    esort[p] = e;
}

// ---------------------------------------------------------------------------
// E3 helper: one wave aggregates one dst row for one etype.
// lane owns 8 channels (16B V load); edge/src ids prefetched 64-wide and
// broadcast via shuffle. acc[8] per lane.
// ---------------------------------------------------------------------------
static __device__ __forceinline__ void wave_agg_etype(
        int d, int lane, int hh,
        const int* __restrict__ src, const int* __restrict__ es,
        const int* __restrict__ offs, const int* __restrict__ deg,
        const float* __restrict__ den, const float* __restrict__ wbuf,
        const ushort_t* __restrict__ V, float* acc /*[8]*/, int* dg_out) {
    int dg = deg[d];
    int o0 = offs[d];
    *dg_out = dg;
    for (int base = 0; base < dg; base += 64) {
        int idx = base + lane;
        int ci = idx < dg ? idx : dg - 1;
        int el = es[o0 + ci];     // coalesced 64-wide prefetch
        int sl = src[el];
        int kmax = dg - base; if (kmax > 64) kmax = 64;
        for (int k = 0; k < kmax; k++) {
            int e = __shfl(el, k);
            int s = __shfl(sl, k);
            float wv = wbuf[e * 8 + hh];
            uint4 vv = *(const uint4*)(V + (size_t)s * HDIM + lane * 8);
            acc[0] += bf2f(vv.x & 0xffff) * wv;
            acc[1] += bf2f(vv.x >> 16) * wv;
            acc[2] += bf2f(vv.y & 0xffff) * wv;
            acc[3] += bf2f(vv.y >> 16) * wv;
            acc[4] += bf2f(vv.z & 0xffff) * wv;
            acc[5] += bf2f(vv.z >> 16) * wv;
            acc[6] += bf2f(vv.w & 0xffff) * wv;
            acc[7] += bf2f(vv.w >> 16) * wv;
        }
    }
}

// E3 (item): one wave per dst; block = 4 waves; grid = NITEM/4
__global__ void agg_item_kernel(const int* __restrict__ src, const int* __restrict__ esort,
                                const int* __restrict__ offs, const int* __restrict__ deg,
                                const float* __restrict__ den, const float* __restrict__ wbuf,
                                const ushort_t* __restrict__ V, void* __restrict__ outv,
                                const int* __restrict__ flag) {
    int lane = threadIdx.x & 63;
    int d = blockIdx.x * 4 + (threadIdx.x >> 6);
    int hh = lane >> 3;
    float acc[8] = {};
    int dg;
    wave_agg_etype(d, lane, hh, src, esort, offs, deg, den, wbuf, V, acc, &dg);
    float inv = dg > 0 ? 1.0f / (den[d * 8 + hh] * (float)dg) : 0.f;
    size_t base = (size_t)NUSER * HDIM + (size_t)d * HDIM + lane * 8;  // h_item after h_user
    if (*flag) {
        float* o = (float*)outv + base;
#pragma unroll
        for (int j = 0; j < 8; j++) o[j] = acc[j] * inv;
    } else {
        uint4 o;
        o.x = (unsigned)f2bf(acc[0] * inv) | ((unsigned)f2bf(acc[1] * inv) << 16);
        o.y = (unsigned)f2bf(acc[2] * inv) | ((unsigned)f2bf(acc[3] * inv) << 16);
        o.z = (unsigned)f2bf(acc[4] * inv) | ((unsigned)f2bf(acc[5] * inv) << 16);
        o.w = (unsigned)f2bf(acc[6] * inv) | ((unsigned)f2bf(acc[7] * inv) << 16);
        *(uint4*)((ushort_t*)outv + base) = o;
    }
}

// E3 (user): fuses clicked_by (v_i) + follows (v_u); one wave per dst
__global__ void agg_user_kernel(
        const int* __restrict__ src1, const int* __restrict__ es1, const int* __restrict__ offs1,
        const int* __restrict__ deg1, const float* __restrict__ den1, const float* __restrict__ w1,
        const ushort_t* __restrict__ V1,
        const int* __restrict__ src2, const int* __restrict__ es2, const int* __restrict__ offs2,
        const int* __restrict__ deg2, const float* __restrict__ den2, const float* __restrict__ w2,
        const ushort_t* __restrict__ V2,
        void* __restrict__ outv, const int* __restrict__ flag) {
    int lane = threadIdx.x & 63;
    int d = blockIdx.x * 4 + (threadIdx.x >> 6);
    int hh = lane >> 3;
    float acc1[8] = {}, acc2[8] = {};
    int dg1, dg2;
    wave_agg_etype(d, lane, hh, src1, es1, offs1, deg1, den1, w1, V1, acc1, &dg1);
    wave_agg_etype(d, lane, hh, src2, es2, offs2, deg2, den2, w2, V2, acc2, &dg2);
    float inv1 = dg1 > 0 ? 1.0f / (den1[d * 8 + hh] * (float)dg1) : 0.f;
    float inv2 = dg2 > 0 ? 1.0f / (den2[d * 8 + hh] * (float)dg2) : 0.f;
    float r[8];
#pragma unroll
    for (int j = 0; j < 8; j++) r[j] = acc1[j] * inv1 + acc2[j] * inv2;
    size_t base = (size_t)d * HDIM + lane * 8;
    if (*flag) {
        float* o = (float*)outv + base;
#pragma unroll
        for (int j = 0; j < 8; j++) o[j] = r[j];
    } else {
        uint4 o;
        o.x = (unsigned)f2bf(r[0]) | ((unsigned)f2bf(r[1]) << 16);
        o.y = (unsigned)f2bf(r[2]) | ((unsigned)f2bf(r[3]) << 16);
        o.z = (unsigned)f2bf(r[4]) | ((unsigned)f2bf(r[5]) << 16);
        o.w = (unsigned)f2bf(r[6]) | ((unsigned)f2bf(r[7]) << 16);
        *(uint4*)((ushort_t*)outv + base) = o;
    }
}

// ---------------------------------------------------------------------------
// kernel_launch
// ---------------------------------------------------------------------------
extern "C" void kernel_launch(void* const* d_in, const int* in_sizes, int n_in,
                              void* d_out, int out_size, void* d_ws, size_t ws_size,
                              hipStream_t stream) {
    const void* x_user  = d_in[0];
    const void* x_item  = d_in[1];
    const void* Wq_user = d_in[2];
    const void* bq_user = d_in[3];
    const void* Wk_user = d_in[4];
    const void* bk_user = d_in[5];
    const void* Wv_user = d_in[6];
    const void* bv_user = d_in[7];
    const void* Wq_item = d_in[8];
    const void* bq_item = d_in[9];
    const void* Wk_item = d_in[10];
    const void* bk_item = d_in[11];
    const void* Wv_item = d_in[12];
    const void* bv_item = d_in[13];
    const void* wa_user = d_in[14];
    const void* wa_item = d_in[15];
    const int* src_clicks     = (const int*)d_in[16];
    const int* dst_clicks     = (const int*)d_in[17];
    const int* src_clicked_by = (const int*)d_in[18];
    const int* dst_clicked_by = (const int*)d_in[19];
    const int* src_follows    = (const int*)d_in[20];
    const int* dst_follows    = (const int*)d_in[21];

    // workspace layout (bytes)
    char* ws = (char*)d_ws;
    ushort_t* v_u  = (ushort_t*)(ws + 0);           // 51,200,000
    ushort_t* v_i  = (ushort_t*)(ws + 51200000);    // 51,200,000
    float* aq_u    = (float*)(ws + 102400000);      // 1,600,000 each
    float* ak_u    = (float*)(ws + 104000000);
    float* aq_i    = (float*)(ws + 105600000);
    float* ak_i    = (float*)(ws + 107200000);
    float* weff_u  = (float*)(ws + 108800000);      // 16 KB (q rows 0-7, k rows 8-15)
    float* weff_i  = (float*)(ws + 108816384);      // 16 KB
    float* beff_u  = (float*)(ws + 108832768);      // 64 B (16 floats)
    float* beff_i  = (float*)(ws + 108832832);      // 64 B
    int*   dflag   = (int*)(ws + 108832896);        // 64 B (dtype flag)
    const size_t Z = 108832960;                     // zero-init region start
    float* den0 = (float*)(ws + Z + 0);             // 1,600,000 each
    float* den1 = (float*)(ws + Z + 1600000);
    float* den2 = (float*)(ws + Z + 3200000);
    int* deg0   = (int*)(ws + Z + 4800000);         // 200,000 each
    int* deg1   = (int*)(ws + Z + 5000000);
    int* deg2   = (int*)(ws + Z + 5200000);
    int* cur0   = (int*)(ws + Z + 5400000);
    int* cur1   = (int*)(ws + Z + 5600000);
    int* cur2   = (int*)(ws + Z + 5800000);
    const size_t ZLEN = 6000000;
    int* offs0  = (int*)(ws + Z + 6000000);
    int* offs1  = (int*)(ws + Z + 6200000);
    int* offs2  = (int*)(ws + Z + 6400000);
    int* es0    = (int*)(ws + Z + 6600000);         // 400,000 each
    int* es1    = (int*)(ws + Z + 7000000);
    int* es2    = (int*)(ws + Z + 7400000);
    float* wb0  = (float*)(ws + Z + 7800000);       // 3,200,000 each
    float* wb1  = (float*)(ws + Z + 11000000);
    float* wb2  = (float*)(ws + Z + 14200000);
    if (ws_size < Z + 17400000) return;

    // D0: dtype detect (must run first; consumers branch on dflag)
    detect_kernel<<<1, 256, 0, stream>>>((const ushort_t*)x_user, dflag);

    // zero-init atomic accumulators (den/deg/cur)
    hipMemsetAsync(ws + Z, 0, ZLEN, stream);

    // P0: effective weights (q in rows 0-7, k in rows 8-15 of weff); 8 blocks each
    eff_w_kernel<<<8, 256, 0, stream>>>(Wq_user, bq_user, wa_user, weff_u,        beff_u,     dflag);
    eff_w_kernel<<<8, 256, 0, stream>>>(Wk_user, bk_user, wa_user, weff_u + 2048, beff_u + 8, dflag);
    eff_w_kernel<<<8, 256, 0, stream>>>(Wq_item, bq_item, wa_item, weff_i,        beff_i,     dflag);
    eff_w_kernel<<<8, 256, 0, stream>>>(Wk_item, bk_item, wa_item, weff_i + 2048, beff_i + 8, dflag);

    // P2: v projections — stateless fragment-in-register MFMA GEMM
    int gblocks = 2 * ((NUSER + 127) / 128);   // 782: {128-row chunk} x {256-col group}
    gemm_v3_kernel<<<gblocks, 256, 0, stream>>>(x_user, Wv_user, bv_user, v_u, NUSER, dflag);
    gemm_v3_kernel<<<gblocks, 256, 0, stream>>>(x_item, Wv_item, bv_item, v_i, NITEM, dflag);

    // P1: attention scalars
    attn_scalar_kernel<<<NUSER / 4, 256, 0, stream>>>(x_user, weff_u, beff_u, aq_u, ak_u, dflag);
    attn_scalar_kernel<<<NITEM / 4, 256, 0, stream>>>(x_item, weff_i, beff_i, aq_i, ak_i, dflag);

    // E1: per-edge exp + den/deg. etype0=clicks(dst=item), 1=clicked_by(dst=user), 2=follows(dst=user)
    int eblocks = (NEDGE + 255) / 256;
    edge_pass1_kernel<<<eblocks, 256, 0, stream>>>(src_clicks, dst_clicks, ak_u, aq_i, wb0, den0, deg0);
    edge_pass1_kernel<<<eblocks, 256, 0, stream>>>(src_clicked_by, dst_clicked_by, ak_i, aq_u, wb1, den1, deg1);
    edge_pass1_kernel<<<eblocks, 256, 0, stream>>>(src_follows, dst_follows, ak_u, aq_u, wb2, den2, deg2);

    // scan (all 3 etypes, one launch)
    scan3_kernel<<<3, 1024, 0, stream>>>(deg0, deg1, deg2, offs0, offs1, offs2);

    // E2: dst-sorted edge lists
    edge_scatter_kernel<<<eblocks, 256, 0, stream>>>(dst_clicks, offs0, cur0, es0);
    edge_scatter_kernel<<<eblocks, 256, 0, stream>>>(dst_clicked_by, offs1, cur1, es1);
    edge_scatter_kernel<<<eblocks, 256, 0, stream>>>(dst_follows, offs2, cur2, es2);

    // E3: aggregate. h_item from clicks (v_u); h_user = clicked_by (v_i) + follows (v_u)
    agg_item_kernel<<<NITEM / 4, 256, 0, stream>>>(src_clicks, es0, offs0, deg0, den0, wb0, v_u, d_out, dflag);
    agg_user_kernel<<<NUSER / 4, 256, 0, stream>>>(
        src_clicked_by, es1, offs1, deg1, den1, wb1, v_i,
        src_follows,    es2, offs2, deg2, den2, wb2, v_u,
        d_out, dflag);
}

// Round 3
// 976.202 us; speedup vs baseline: 1.1099x; 1.0083x over previous
//
#include <hip/hip_runtime.h>

// ---------------------------------------------------------------------------
// Problem constants
// ---------------------------------------------------------------------------
#define NUSER 50000
#define NITEM 50000
#define NEDGE 100000
#define HDIM  512      // H*D
#define KIN   256      // input feature dim

typedef unsigned short ushort_t;
typedef __attribute__((ext_vector_type(8))) short short8;
typedef __attribute__((ext_vector_type(4))) float f32x4;

static __device__ __forceinline__ float bf2f(ushort_t u) {
    unsigned v = ((unsigned)u) << 16;
    float f;
    __builtin_memcpy(&f, &v, 4);
    return f;
}
static __device__ __forceinline__ ushort_t f2bf(float f) {
    unsigned u;
    __builtin_memcpy(&u, &f, 4);
    unsigned r = u + 0x7fffu + ((u >> 16) & 1u);  // RNE
    return (ushort_t)(r >> 16);
}
// runtime-dtype scalar load
static __device__ __forceinline__ float ldf(const void* p, long i, bool fp32) {
    return fp32 ? ((const float*)p)[i] : bf2f(((const ushort_t*)p)[i]);
}

static __device__ __forceinline__ short8 pack_bf8(float4 a, float4 b) {
    short8 r;
    r[0] = (short)f2bf(a.x); r[1] = (short)f2bf(a.y);
    r[2] = (short)f2bf(a.z); r[3] = (short)f2bf(a.w);
    r[4] = (short)f2bf(b.x); r[5] = (short)f2bf(b.y);
    r[6] = (short)f2bf(b.z); r[7] = (short)f2bf(b.w);
    return r;
}

#define GLOBAL_AS __attribute__((address_space(1)))
#define LDS_AS    __attribute__((address_space(3)))
static __device__ __forceinline__ void load_lds16(const void* g, void* l) {
    __builtin_amdgcn_global_load_lds((const GLOBAL_AS void*)g, (LDS_AS void*)l, 16, 0, 0);
}

// ---------------------------------------------------------------------------
// D0: runtime dtype detection (0 = bf16, 1 = fp32). fp32 read as bf16 gives
// huge decoded values w.p. ~1 over 4096 samples; bf16 N(0,1) maxes ~4.
// ---------------------------------------------------------------------------
__global__ void detect_kernel(const ushort_t* __restrict__ x, int* __restrict__ flag) {
    __shared__ float red[256];
    int tid = threadIdx.x;
    float m = 0.f;
    for (int i = tid; i < 4096; i += 256) m = fmaxf(m, fabsf(bf2f(x[i])));
    red[tid] = m;
    __syncthreads();
    for (int s = 128; s > 0; s >>= 1) {
        if (tid < s) red[tid] = fmaxf(red[tid], red[tid + s]);
        __syncthreads();
    }
    if (tid == 0) *flag = (red[0] > 1e6f) ? 1 : 0;
}

// ---------------------------------------------------------------------------
// P0: effective attention weights, one block per head (grid = 8).
// weff[h][k] = 0.125 * sum_d wa[d]*W[h*64+d][k];  beff[h] = 0.125 * wa.b[h]
// ---------------------------------------------------------------------------
__global__ void eff_w_kernel(const void* __restrict__ W,   // 512x256
                             const void* __restrict__ b,   // 512
                             const void* __restrict__ wa,  // 64
                             float* __restrict__ weff,     // 8x256
                             float* __restrict__ beff,     // 8
                             const int* __restrict__ flag) {
    bool fp32 = (*flag != 0);
    int h = blockIdx.x;      // 0..7
    int k = threadIdx.x;     // 0..255
    __shared__ float was[64];
    __shared__ float red[64];
    if (k < 64) was[k] = ldf(wa, k, fp32);
    __syncthreads();
    float s = 0.f;
#pragma unroll 8
    for (int d = 0; d < 64; d++)
        s += was[d] * ldf(W, (long)(h * 64 + d) * KIN + k, fp32);
    weff[h * KIN + k] = 0.125f * s;
    if (k < 64) red[k] = was[k] * ldf(b, h * 64 + k, fp32);
    __syncthreads();
    if (k == 0) {
        float t = 0.f;
        for (int d = 0; d < 64; d++) t += red[d];
        beff[h] = 0.125f * t;
    }
}

// ---------------------------------------------------------------------------
// P1: per-node attention scalars aq[n][h], ak[n][h] (pre-scaled by 1/8)
// block 256 = 4 waves, one node per wave. grid = N/4
// ---------------------------------------------------------------------------
__global__ void attn_scalar_kernel(const void* __restrict__ X,     // N x 256
                                   const float* __restrict__ weff, // 16 x 256 (q:0-7, k:8-15)
                                   const float* __restrict__ beff, // 16
                                   float* __restrict__ aq,         // N x 8
                                   float* __restrict__ ak,         // N x 8
                                   const int* __restrict__ flag) {
    __shared__ float wl[16 * KIN];
    int tid = threadIdx.x;
    for (int i = tid; i < 16 * KIN; i += 256) wl[i] = weff[i];
    bool fp32 = (*flag != 0);
    __syncthreads();
    int lane = tid & 63, w = tid >> 6;
    int n = blockIdx.x * 4 + w;
    float xv0, xv1, xv2, xv3;
    if (fp32) {
        const float* xr = (const float*)X + (size_t)n * KIN + lane * 4;
        float4 u = *(const float4*)xr;
        xv0 = u.x; xv1 = u.y; xv2 = u.z; xv3 = u.w;
    } else {
        const ushort_t* xr = (const ushort_t*)X + (size_t)n * KIN + lane * 4;
        uint2 u = *(const uint2*)xr;
        xv0 = bf2f(u.x & 0xffff); xv1 = bf2f(u.x >> 16);
        xv2 = bf2f(u.y & 0xffff); xv3 = bf2f(u.y >> 16);
    }
    float p[16];
#pragma unroll
    for (int o = 0; o < 16; o++) {
        float4 wv = *(const float4*)&wl[o * KIN + lane * 4];
        p[o] = xv0 * wv.x + xv1 * wv.y + xv2 * wv.z + xv3 * wv.w;
    }
#pragma unroll
    for (int o = 0; o < 16; o++) {
        float v = p[o];
#pragma unroll
        for (int m = 32; m > 0; m >>= 1) v += __shfl_xor(v, m);
        if (lane == o) {
            float r = v + beff[o];
            if (o < 8) aq[n * 8 + o] = r;
            else       ak[n * 8 + (o - 8)] = r;
        }
    }
}

// ---------------------------------------------------------------------------
// P2: v projection GEMM v4 — coalescing-first design.
// M=50000, N=512, K=256. Block = 4 waves, covers 64 rows x 256 cols.
// blockIdx.x = rc*2 + cg: rc = 64-row chunk (782), cg = 256-col group (2).
//
// Phases (ONE barrier per block):
//  S) A-tile (64 x 256) staged to LDS in FRAGMENT-MAJOR order:
//     group g=(rt*16+ks*2+half), slot byte = g*1024 + lane*16.
//     bf16: global_load_lds 16B/lane.  fp32: 32B/lane loads + cvt + ds_write_b128.
//     B fragments (wave-private 64-col strip, 4nf x 8ks short8 = 128 VGPR)
//     loaded once from W (one-time cost).
//  C) per 32-row tile rt: ds_read_b128 A-frags (lane-consecutive -> conflict-
//     free), 8 ks x 8 MFMA, accumulation order identical to v3.
//  E) coalesced epilogue: acc -> bf16 into wave-private 4KB LDS scratch,
//     read back row-major, uint4 global stores (128B contiguous per row).
// No inter-wave dependencies after the single barrier.
// ---------------------------------------------------------------------------
__global__ __launch_bounds__(256, 2) void gemm_v4_kernel(
        const void* __restrict__ A, const void* __restrict__ W,
        const void* __restrict__ bias, ushort_t* __restrict__ C, int M,
        const int* __restrict__ flag) {
    __shared__ __align__(16) ushort_t As[16384];     // 32 KB: 32 groups x 64 lanes x 16B
    __shared__ __align__(16) ushort_t ep[4][2048];   // 16 KB: 4KB wave-private C scratch
    bool fp32 = (*flag != 0);
    int tid = threadIdx.x;
    int lane = tid & 63, w = tid >> 6;
    int rc = blockIdx.x >> 1;            // 64-row chunk
    int cg = blockIdx.x & 1;             // 256-col group
    int rb = rc * 64;                    // block row base
    int nf0 = cg * 16 + w * 4;           // wave's first 16-col fragment
    int colq = lane & 15, rq = lane >> 4;
    int kl = rq * 8;                     // k-offset within a 32-slice

    // --- S: stage A tile (fragment-major), 8 groups per wave ---
#pragma unroll
    for (int i = 0; i < 8; i++) {
        int g = w * 8 + i;               // 0..31
        int rt = g >> 4, ks = (g >> 1) & 7, half = g & 1;
        int row = rb + rt * 32 + half * 16 + colq;
        if (row > M - 1) row = M - 1;    // clamp (stores are guarded later)
        if (fp32) {
            const float* p = (const float*)A + (size_t)row * KIN + ks * 32 + kl;
            short8 v = pack_bf8(*(const float4*)p, *(const float4*)(p + 4));
            *(short8*)&As[g * 512 + lane * 8] = v;
        } else {
            load_lds16((const ushort_t*)A + (size_t)row * KIN + ks * 32 + kl,
                       &As[g * 512 + lane * 8]);
        }
    }

    // --- B fragments, converted once into registers: breg[nf][ks] ---
    short8 breg[4][8];
#pragma unroll
    for (int nf = 0; nf < 4; nf++) {
        int col = (nf0 + nf) * 16 + colq;    // W row index (= output column)
#pragma unroll
        for (int ks = 0; ks < 8; ks++) {
            int k0 = ks * 32 + kl;
            if (fp32) {
                const float* p = (const float*)W + (size_t)col * KIN + k0;
                breg[nf][ks] = pack_bf8(*(const float4*)p, *(const float4*)(p + 4));
            } else {
                breg[nf][ks] = *(const short8*)((const ushort_t*)W + (size_t)col * KIN + k0);
            }
        }
    }
    float bv[4];
#pragma unroll
    for (int nf = 0; nf < 4; nf++)
        bv[nf] = ldf(bias, (nf0 + nf) * 16 + colq, fp32);

    __syncthreads();   // single barrier: A tile visible to all waves

    // --- C + E: two 32-row tiles ---
#pragma unroll
    for (int rt = 0; rt < 2; rt++) {
        f32x4 acc[2][4] = {};
#pragma unroll
        for (int ks = 0; ks < 8; ks++) {
            short8 a0 = *(const short8*)&As[(rt * 16 + ks * 2 + 0) * 512 + lane * 8];
            short8 a1 = *(const short8*)&As[(rt * 16 + ks * 2 + 1) * 512 + lane * 8];
#pragma unroll
            for (int nf = 0; nf < 4; nf++) {
                acc[0][nf] = __builtin_amdgcn_mfma_f32_16x16x32_bf16(a0, breg[nf][ks], acc[0][nf], 0, 0, 0);
                acc[1][nf] = __builtin_amdgcn_mfma_f32_16x16x32_bf16(a1, breg[nf][ks], acc[1][nf], 0, 0, 0);
            }
        }
        // epilogue: acc -> wave-private LDS (bf16), then coalesced 16B stores
#pragma unroll
        for (int mi = 0; mi < 2; mi++)
#pragma unroll
            for (int r = 0; r < 4; r++)
#pragma unroll
                for (int nf = 0; nf < 4; nf++)
                    ep[w][(mi * 16 + rq * 4 + r) * 64 + nf * 16 + colq] =
                        f2bf(acc[mi][nf][r] + bv[nf]);
#pragma unroll
        for (int j = 0; j < 4; j++) {
            int idx = j * 64 + lane;         // 256 chunks of 16B
            int rl = idx >> 3;               // local row 0..31
            int cb = (idx & 7) * 8;          // ushort offset in row, 0..56
            int grow = rb + rt * 32 + rl;
            if (grow < M)
                *(uint4*)(C + (size_t)grow * HDIM + cg * 256 + w * 64 + cb) =
                    *(const uint4*)&ep[w][rl * 64 + cb];
        }
    }
}

// ---------------------------------------------------------------------------
// E1: per-edge exp weights + denominator + degree
// ---------------------------------------------------------------------------
__global__ void edge_pass1_kernel(const int* __restrict__ src, const int* __restrict__ dst,
                                  const float* __restrict__ ak,   // src-ntype, N x 8
                                  const float* __restrict__ aq,   // dst-ntype, N x 8
                                  float* __restrict__ wbuf,       // E x 8
                                  float* __restrict__ den,        // Nd x 8 (zeroed)
                                  int* __restrict__ deg) {        // Nd (zeroed)
    int e = blockIdx.x * 256 + threadIdx.x;
    if (e >= NEDGE) return;
    int s = src[e], d = dst[e];
#pragma unroll
    for (int h = 0; h < 8; h++) {
        float sc = ak[s * 8 + h] + aq[d * 8 + h];
        float wv = __expf(sc);
        wbuf[e * 8 + h] = wv;
        atomicAdd(&den[d * 8 + h], wv);
    }
    atomicAdd(&deg[d], 1);
}

// ---------------------------------------------------------------------------
// Scan: exclusive prefix sum of deg -> offs, 3 edge types, one launch
// ---------------------------------------------------------------------------
__global__ void scan3_kernel(const int* __restrict__ deg0, const int* __restrict__ deg1,
                             const int* __restrict__ deg2, int* __restrict__ offs0,
                             int* __restrict__ offs1, int* __restrict__ offs2) {
    const int Nd = NUSER;
    const int* deg = blockIdx.x == 0 ? deg0 : (blockIdx.x == 1 ? deg1 : deg2);
    int* offs = blockIdx.x == 0 ? offs0 : (blockIdx.x == 1 ? offs1 : offs2);
    __shared__ int lds[1024];
    int tid = threadIdx.x;
    int chunk = (Nd + 1023) >> 10;
    int s = tid * chunk;
    int e = s + chunk; if (e > Nd) e = Nd;
    int local = 0;
    for (int i = s; i < e; i++) local += deg[i];
    lds[tid] = local;
    __syncthreads();
    for (int d = 1; d < 1024; d <<= 1) {
        int v = (tid >= d) ? lds[tid - d] : 0;
        __syncthreads();
        lds[tid] += v;
        __syncthreads();
    }
    int run = (tid > 0) ? lds[tid - 1] : 0;
    for (int i = s; i < e; i++) { offs[i] = run; run += deg[i]; }
}

// ---------------------------------------------------------------------------
// E2: scatter edge ids into dst-sorted order
// ---------------------------------------------------------------------------
__global__ void edge_scatter_kernel(const int* __restrict__ dst, const int* __restrict__ offs,
                                    int* __restrict__ cur, int* __restrict__ esort) {
    int e = blockIdx.x * 256 + threadIdx.x;
    if (e >= NEDGE) return;
    int d = dst[e];
    int p = offs[d] + atomicAdd(&cur[d], 1);
    esort[p] = e;
}

// ---------------------------------------------------------------------------
// E3 helper: one wave aggregates one dst row for one etype.
// lane owns 8 channels (16B V load); edge/src ids prefetched 64-wide and
// broadcast via shuffle. acc[8] per lane.
// ---------------------------------------------------------------------------
static __device__ __forceinline__ void wave_agg_etype(
        int d, int lane, int hh,
        const int* __restrict__ src, const int* __restrict__ es,
        const int* __restrict__ offs, const int* __restrict__ deg,
        const float* __restrict__ den, const float* __restrict__ wbuf,
        const ushort_t* __restrict__ V, float* acc /*[8]*/, int* dg_out) {
    int dg = deg[d];
    int o0 = offs[d];
    *dg_out = dg;
    for (int base = 0; base < dg; base += 64) {
        int idx = base + lane;
        int ci = idx < dg ? idx : dg - 1;
        int el = es[o0 + ci];     // coalesced 64-wide prefetch
        int sl = src[el];
        int kmax = dg - base; if (kmax > 64) kmax = 64;
        for (int k = 0; k < kmax; k++) {
            int e = __shfl(el, k);
            int s = __shfl(sl, k);
            float wv = wbuf[e * 8 + hh];
            uint4 vv = *(const uint4*)(V + (size_t)s * HDIM + lane * 8);
            acc[0] += bf2f(vv.x & 0xffff) * wv;
            acc[1] += bf2f(vv.x >> 16) * wv;
            acc[2] += bf2f(vv.y & 0xffff) * wv;
            acc[3] += bf2f(vv.y >> 16) * wv;
            acc[4] += bf2f(vv.z & 0xffff) * wv;
            acc[5] += bf2f(vv.z >> 16) * wv;
            acc[6] += bf2f(vv.w & 0xffff) * wv;
            acc[7] += bf2f(vv.w >> 16) * wv;
        }
    }
}

// E3 (item): one wave per dst; block = 4 waves; grid = NITEM/4
__global__ void agg_item_kernel(const int* __restrict__ src, const int* __restrict__ esort,
                                const int* __restrict__ offs, const int* __restrict__ deg,
                                const float* __restrict__ den, const float* __restrict__ wbuf,
                                const ushort_t* __restrict__ V, void* __restrict__ outv,
                                const int* __restrict__ flag) {
    int lane = threadIdx.x & 63;
    int d = blockIdx.x * 4 + (threadIdx.x >> 6);
    int hh = lane >> 3;
    float acc[8] = {};
    int dg;
    wave_agg_etype(d, lane, hh, src, esort, offs, deg, den, wbuf, V, acc, &dg);
    float inv = dg > 0 ? 1.0f / (den[d * 8 + hh] * (float)dg) : 0.f;
    size_t base = (size_t)NUSER * HDIM + (size_t)d * HDIM + lane * 8;  // h_item after h_user
    if (*flag) {
        float* o = (float*)outv + base;
#pragma unroll
        for (int j = 0; j < 8; j++) o[j] = acc[j] * inv;
    } else {
        uint4 o;
        o.x = (unsigned)f2bf(acc[0] * inv) | ((unsigned)f2bf(acc[1] * inv) << 16);
        o.y = (unsigned)f2bf(acc[2] * inv) | ((unsigned)f2bf(acc[3] * inv) << 16);
        o.z = (unsigned)f2bf(acc[4] * inv) | ((unsigned)f2bf(acc[5] * inv) << 16);
        o.w = (unsigned)f2bf(acc[6] * inv) | ((unsigned)f2bf(acc[7] * inv) << 16);
        *(uint4*)((ushort_t*)outv + base) = o;
    }
}

// E3 (user): fuses clicked_by (v_i) + follows (v_u); one wave per dst
__global__ void agg_user_kernel(
        const int* __restrict__ src1, const int* __restrict__ es1, const int* __restrict__ offs1,
        const int* __restrict__ deg1, const float* __restrict__ den1, const float* __restrict__ w1,
        const ushort_t* __restrict__ V1,
        const int* __restrict__ src2, const int* __restrict__ es2, const int* __restrict__ offs2,
        const int* __restrict__ deg2, const float* __restrict__ den2, const float* __restrict__ w2,
        const ushort_t* __restrict__ V2,
        void* __restrict__ outv, const int* __restrict__ flag) {
    int lane = threadIdx.x & 63;
    int d = blockIdx.x * 4 + (threadIdx.x >> 6);
    int hh = lane >> 3;
    float acc1[8] = {}, acc2[8] = {};
    int dg1, dg2;
    wave_agg_etype(d, lane, hh, src1, es1, offs1, deg1, den1, w1, V1, acc1, &dg1);
    wave_agg_etype(d, lane, hh, src2, es2, offs2, deg2, den2, w2, V2, acc2, &dg2);
    float inv1 = dg1 > 0 ? 1.0f / (den1[d * 8 + hh] * (float)dg1) : 0.f;
    float inv2 = dg2 > 0 ? 1.0f / (den2[d * 8 + hh] * (float)dg2) : 0.f;
    float r[8];
#pragma unroll
    for (int j = 0; j < 8; j++) r[j] = acc1[j] * inv1 + acc2[j] * inv2;
    size_t base = (size_t)d * HDIM + lane * 8;
    if (*flag) {
        float* o = (float*)outv + base;
#pragma unroll
        for (int j = 0; j < 8; j++) o[j] = r[j];
    } else {
        uint4 o;
        o.x = (unsigned)f2bf(r[0]) | ((unsigned)f2bf(r[1]) << 16);
        o.y = (unsigned)f2bf(r[2]) | ((unsigned)f2bf(r[3]) << 16);
        o.z = (unsigned)f2bf(r[4]) | ((unsigned)f2bf(r[5]) << 16);
        o.w = (unsigned)f2bf(r[6]) | ((unsigned)f2bf(r[7]) << 16);
        *(uint4*)((ushort_t*)outv + base) = o;
    }
}

// ---------------------------------------------------------------------------
// kernel_launch
// ---------------------------------------------------------------------------
extern "C" void kernel_launch(void* const* d_in, const int* in_sizes, int n_in,
                              void* d_out, int out_size, void* d_ws, size_t ws_size,
                              hipStream_t stream) {
    const void* x_user  = d_in[0];
    const void* x_item  = d_in[1];
    const void* Wq_user = d_in[2];
    const void* bq_user = d_in[3];
    const void* Wk_user = d_in[4];
    const void* bk_user = d_in[5];
    const void* Wv_user = d_in[6];
    const void* bv_user = d_in[7];
    const void* Wq_item = d_in[8];
    const void* bq_item = d_in[9];
    const void* Wk_item = d_in[10];
    const void* bk_item = d_in[11];
    const void* Wv_item = d_in[12];
    const void* bv_item = d_in[13];
    const void* wa_user = d_in[14];
    const void* wa_item = d_in[15];
    const int* src_clicks     = (const int*)d_in[16];
    const int* dst_clicks     = (const int*)d_in[17];
    const int* src_clicked_by = (const int*)d_in[18];
    const int* dst_clicked_by = (const int*)d_in[19];
    const int* src_follows    = (const int*)d_in[20];
    const int* dst_follows    = (const int*)d_in[21];

    // workspace layout (bytes)
    char* ws = (char*)d_ws;
    ushort_t* v_u  = (ushort_t*)(ws + 0);           // 51,200,000
    ushort_t* v_i  = (ushort_t*)(ws + 51200000);    // 51,200,000
    float* aq_u    = (float*)(ws + 102400000);      // 1,600,000 each
    float* ak_u    = (float*)(ws + 104000000);
    float* aq_i    = (float*)(ws + 105600000);
    float* ak_i    = (float*)(ws + 107200000);
    float* weff_u  = (float*)(ws + 108800000);      // 16 KB (q rows 0-7, k rows 8-15)
    float* weff_i  = (float*)(ws + 108816384);      // 16 KB
    float* beff_u  = (float*)(ws + 108832768);      // 64 B (16 floats)
    float* beff_i  = (float*)(ws + 108832832);      // 64 B
    int*   dflag   = (int*)(ws + 108832896);        // 64 B (dtype flag)
    const size_t Z = 108832960;                     // zero-init region start
    float* den0 = (float*)(ws + Z + 0);             // 1,600,000 each
    float* den1 = (float*)(ws + Z + 1600000);
    float* den2 = (float*)(ws + Z + 3200000);
    int* deg0   = (int*)(ws + Z + 4800000);         // 200,000 each
    int* deg1   = (int*)(ws + Z + 5000000);
    int* deg2   = (int*)(ws + Z + 5200000);
    int* cur0   = (int*)(ws + Z + 5400000);
    int* cur1   = (int*)(ws + Z + 5600000);
    int* cur2   = (int*)(ws + Z + 5800000);
    const size_t ZLEN = 6000000;
    int* offs0  = (int*)(ws + Z + 6000000);
    int* offs1  = (int*)(ws + Z + 6200000);
    int* offs2  = (int*)(ws + Z + 6400000);
    int* es0    = (int*)(ws + Z + 6600000);         // 400,000 each
    int* es1    = (int*)(ws + Z + 7000000);
    int* es2    = (int*)(ws + Z + 7400000);
    float* wb0  = (float*)(ws + Z + 7800000);       // 3,200,000 each
    float* wb1  = (float*)(ws + Z + 11000000);
    float* wb2  = (float*)(ws + Z + 14200000);
    if (ws_size < Z + 17400000) return;

    // D0: dtype detect (must run first; consumers branch on dflag)
    detect_kernel<<<1, 256, 0, stream>>>((const ushort_t*)x_user, dflag);

    // zero-init atomic accumulators (den/deg/cur)
    hipMemsetAsync(ws + Z, 0, ZLEN, stream);

    // P0: effective weights (q in rows 0-7, k in rows 8-15 of weff); 8 blocks each
    eff_w_kernel<<<8, 256, 0, stream>>>(Wq_user, bq_user, wa_user, weff_u,        beff_u,     dflag);
    eff_w_kernel<<<8, 256, 0, stream>>>(Wk_user, bk_user, wa_user, weff_u + 2048, beff_u + 8, dflag);
    eff_w_kernel<<<8, 256, 0, stream>>>(Wq_item, bq_item, wa_item, weff_i,        beff_i,     dflag);
    eff_w_kernel<<<8, 256, 0, stream>>>(Wk_item, bk_item, wa_item, weff_i + 2048, beff_i + 8, dflag);

    // P2: v projections — coalescing-first MFMA GEMM (1 barrier/block)
    int gblocks = 2 * ((NUSER + 63) / 64);   // 1564: {64-row chunk} x {256-col group}
    gemm_v4_kernel<<<gblocks, 256, 0, stream>>>(x_user, Wv_user, bv_user, v_u, NUSER, dflag);
    gemm_v4_kernel<<<gblocks, 256, 0, stream>>>(x_item, Wv_item, bv_item, v_i, NITEM, dflag);

    // P1: attention scalars
    attn_scalar_kernel<<<NUSER / 4, 256, 0, stream>>>(x_user, weff_u, beff_u, aq_u, ak_u, dflag);
    attn_scalar_kernel<<<NITEM / 4, 256, 0, stream>>>(x_item, weff_i, beff_i, aq_i, ak_i, dflag);

    // E1: per-edge exp + den/deg. etype0=clicks(dst=item), 1=clicked_by(dst=user), 2=follows(dst=user)
    int eblocks = (NEDGE + 255) / 256;
    edge_pass1_kernel<<<eblocks, 256, 0, stream>>>(src_clicks, dst_clicks, ak_u, aq_i, wb0, den0, deg0);
    edge_pass1_kernel<<<eblocks, 256, 0, stream>>>(src_clicked_by, dst_clicked_by, ak_i, aq_u, wb1, den1, deg1);
    edge_pass1_kernel<<<eblocks, 256, 0, stream>>>(src_follows, dst_follows, ak_u, aq_u, wb2, den2, deg2);

    // scan (all 3 etypes, one launch)
    scan3_kernel<<<3, 1024, 0, stream>>>(deg0, deg1, deg2, offs0, offs1, offs2);

    // E2: dst-sorted edge lists
    edge_scatter_kernel<<<eblocks, 256, 0, stream>>>(dst_clicks, offs0, cur0, es0);
    edge_scatter_kernel<<<eblocks, 256, 0, stream>>>(dst_clicked_by, offs1, cur1, es1);
    edge_scatter_kernel<<<eblocks, 256, 0, stream>>>(dst_follows, offs2, cur2, es2);

    // E3: aggregate. h_item from clicks (v_u); h_user = clicked_by (v_i) + follows (v_u)
    agg_item_kernel<<<NITEM / 4, 256, 0, stream>>>(src_clicks, es0, offs0, deg0, den0, wb0, v_u, d_out, dflag);
    agg_user_kernel<<<NUSER / 4, 256, 0, stream>>>(
        src_clicked_by, es1, offs1, deg1, den1, wb1, v_i,
        src_follows,    es2, offs2, deg2, den2, wb2, v_u,
        d_out, dflag);
}

// Round 4
// 836.458 us; speedup vs baseline: 1.2953x; 1.1671x over previous
//
#include <hip/hip_runtime.h>

// ---------------------------------------------------------------------------
// Problem constants
// ---------------------------------------------------------------------------
#define NUSER 50000
#define NITEM 50000
#define NEDGE 100000
#define HDIM  512      // H*D
#define KIN   256      // input feature dim

typedef unsigned short ushort_t;
typedef __attribute__((ext_vector_type(8))) short short8;
typedef __attribute__((ext_vector_type(4))) float f32x4;

static __device__ __forceinline__ float bf2f(ushort_t u) {
    unsigned v = ((unsigned)u) << 16;
    float f;
    __builtin_memcpy(&f, &v, 4);
    return f;
}
static __device__ __forceinline__ ushort_t f2bf(float f) {
    unsigned u;
    __builtin_memcpy(&u, &f, 4);
    unsigned r = u + 0x7fffu + ((u >> 16) & 1u);  // RNE
    return (ushort_t)(r >> 16);
}
// runtime-dtype scalar load
static __device__ __forceinline__ float ldf(const void* p, long i, bool fp32) {
    return fp32 ? ((const float*)p)[i] : bf2f(((const ushort_t*)p)[i]);
}

// ---------------------------------------------------------------------------
// D0: runtime dtype detection (0 = bf16, 1 = fp32)
// ---------------------------------------------------------------------------
__global__ void detect_kernel(const ushort_t* __restrict__ x, int* __restrict__ flag) {
    __shared__ float red[256];
    int tid = threadIdx.x;
    float m = 0.f;
    for (int i = tid; i < 4096; i += 256) m = fmaxf(m, fabsf(bf2f(x[i])));
    red[tid] = m;
    __syncthreads();
    for (int s = 128; s > 0; s >>= 1) {
        if (tid < s) red[tid] = fmaxf(red[tid], red[tid + s]);
        __syncthreads();
    }
    if (tid == 0) *flag = (red[0] > 1e6f) ? 1 : 0;
}

// ---------------------------------------------------------------------------
// P0 (fused x4): effective attention weights. grid = (8 heads, 4 targets).
// y: 0=q_user 1=k_user 2=q_item 3=k_item
// ---------------------------------------------------------------------------
__global__ void eff_w_all_kernel(
        const void* __restrict__ Wqu, const void* __restrict__ bqu,
        const void* __restrict__ Wku, const void* __restrict__ bku,
        const void* __restrict__ Wqi, const void* __restrict__ bqi,
        const void* __restrict__ Wki, const void* __restrict__ bki,
        const void* __restrict__ wau, const void* __restrict__ wai,
        float* __restrict__ weffu, float* __restrict__ weffi,
        float* __restrict__ beffu, float* __restrict__ beffi,
        const int* __restrict__ flag) {
    int y = blockIdx.y;
    const void* W  = (y == 0) ? Wqu : (y == 1) ? Wku : (y == 2) ? Wqi : Wki;
    const void* b  = (y == 0) ? bqu : (y == 1) ? bku : (y == 2) ? bqi : bki;
    const void* wa = (y < 2) ? wau : wai;
    float* weff = ((y < 2) ? weffu : weffi) + (y & 1) * 2048;
    float* beff = ((y < 2) ? beffu : beffi) + (y & 1) * 8;
    bool fp32 = (*flag != 0);
    int h = blockIdx.x;      // 0..7
    int k = threadIdx.x;     // 0..255
    __shared__ float was[64];
    __shared__ float red[64];
    if (k < 64) was[k] = ldf(wa, k, fp32);
    __syncthreads();
    float s = 0.f;
#pragma unroll 8
    for (int d = 0; d < 64; d++)
        s += was[d] * ldf(W, (long)(h * 64 + d) * KIN + k, fp32);
    weff[h * KIN + k] = 0.125f * s;
    if (k < 64) red[k] = was[k] * ldf(b, h * 64 + k, fp32);
    __syncthreads();
    if (k == 0) {
        float t = 0.f;
        for (int d = 0; d < 64; d++) t += red[d];
        beff[h] = 0.125f * t;
    }
}

// ---------------------------------------------------------------------------
// GEMM v5 helpers: coalesced staging into rotation-swizzled row-major LDS.
// LDS layout: 64 rows x 512 B (bf16). In-row byte of k-element kk (2B) is
//   (kk*2 + (row&7)*64) mod 512  — bijective per row, spreads the 16-row
// fragment read across banks (2-way residual = free).
// ---------------------------------------------------------------------------
static __device__ __forceinline__ void stage_tile_fp32(
        const float* __restrict__ G, ushort_t* lds, int base_row, int maxrow, int tid) {
    int lane = tid & 63, w = tid >> 6;
#pragma unroll
    for (int i = 0; i < 16; i++) {
        int row_l = i * 4 + w;                       // one full row per wave-instr
        int grow = base_row + row_l; if (grow > maxrow) grow = maxrow;
        float4 v = *(const float4*)(G + (size_t)grow * KIN + lane * 4);
        uint2 u;
        u.x = (unsigned)f2bf(v.x) | ((unsigned)f2bf(v.y) << 16);
        u.y = (unsigned)f2bf(v.z) | ((unsigned)f2bf(v.w) << 16);
        int byte = row_l * 512 + ((lane * 8 + ((row_l & 7) << 6)) & 511);
        *(uint2*)((char*)lds + byte) = u;
    }
}
static __device__ __forceinline__ void stage_tile_bf16(
        const ushort_t* __restrict__ G, ushort_t* lds, int base_row, int maxrow, int tid) {
#pragma unroll
    for (int i = 0; i < 8; i++) {
        int chunk = i * 256 + tid;                   // 16B chunks, 32 per row
        int row_l = chunk >> 5, hw = chunk & 31;
        int grow = base_row + row_l; if (grow > maxrow) grow = maxrow;
        uint4 v = *(const uint4*)(G + (size_t)grow * KIN + hw * 8);
        int byte = row_l * 512 + ((hw * 16 + ((row_l & 7) << 6)) & 511);
        *(uint4*)((char*)lds + byte) = v;
    }
}
// fragment read: lane (colq,rq) gets k = ks*32 + rq*8 .. +7 of row_l
static __device__ __forceinline__ short8 frag_read(const ushort_t* lds, int row_l,
                                                   int ks, int rq) {
    int byte = row_l * 512 + (((ks * 64 + rq * 16) + ((row_l & 7) << 6)) & 511);
    return *(const short8*)((const char*)lds + byte);
}

// ---------------------------------------------------------------------------
// P2 (fused x2): v projection GEMM v5. grid = (512, 2); y selects user/item.
// Block: cg = b&1 (256-col group), rc0 = b>>1; loops rc += 256 over 782
// 64-row chunks (~3 per block -> B regs amortized, ~2 blocks/CU).
// Per wave: B frags (64-col strip) in 128 VGPRs, staged coalesced via a
// shared quarter buffer; per rc: A staged coalesced+swizzled, 2x(8 ks x 8
// MFMA) with accumulation order identical to v3/v4; coalesced uint4 C store
// through a bank-rotated wave-private scratch.
// ---------------------------------------------------------------------------
__global__ __launch_bounds__(256, 2) void gemm_v5_kernel(
        const void* __restrict__ Au, const void* __restrict__ Wu,
        const void* __restrict__ bu, ushort_t* __restrict__ Cu,
        const void* __restrict__ Ai, const void* __restrict__ Wi,
        const void* __restrict__ bi, ushort_t* __restrict__ Ci,
        int M, const int* __restrict__ flag) {
    __shared__ __align__(16) ushort_t As[64 * 256];   // 32 KB
    __shared__ __align__(16) ushort_t Bs[64 * 256];   // 32 KB
    __shared__ __align__(16) ushort_t ep[4][2048];    // 16 KB
    const void* A    = blockIdx.y ? Ai : Au;
    const void* W    = blockIdx.y ? Wi : Wu;
    const void* bias = blockIdx.y ? bi : bu;
    ushort_t* C      = blockIdx.y ? Ci : Cu;
    bool fp32 = (*flag != 0);
    int tid = threadIdx.x, lane = tid & 63, w = tid >> 6;
    int b = blockIdx.x, cg = b & 1, rc0 = b >> 1;
    int colq = lane & 15, rq = lane >> 4;
    int nf0 = cg * 16 + w * 4;

    // first A tile staged early; completes under the B-quarter barriers
    if (fp32) stage_tile_fp32((const float*)A, As, rc0 * 64, M - 1, tid);
    else      stage_tile_bf16((const ushort_t*)A, As, rc0 * 64, M - 1, tid);

    // B: W strip quarter-by-quarter through Bs; wave q keeps quarter q in regs
    short8 breg[4][8];
#pragma unroll
    for (int q = 0; q < 4; q++) {
        if (fp32) stage_tile_fp32((const float*)W, Bs, cg * 256 + q * 64, 511, tid);
        else      stage_tile_bf16((const ushort_t*)W, Bs, cg * 256 + q * 64, 511, tid);
        __syncthreads();
        if (w == q) {
#pragma unroll
            for (int nf = 0; nf < 4; nf++)
#pragma unroll
                for (int ks = 0; ks < 8; ks++)
                    breg[nf][ks] = frag_read(Bs, nf * 16 + colq, ks, rq);
        }
        __syncthreads();
    }
    float bv[4];
#pragma unroll
    for (int nf = 0; nf < 4; nf++)
        bv[nf] = ldf(bias, (nf0 + nf) * 16 + colq, fp32);

    bool first = true;
    for (int rc = rc0; rc < 782; rc += 256) {
        if (!first) {
            __syncthreads();       // prior iter's frag reads done
            if (fp32) stage_tile_fp32((const float*)A, As, rc * 64, M - 1, tid);
            else      stage_tile_bf16((const ushort_t*)A, As, rc * 64, M - 1, tid);
            __syncthreads();
        }
        first = false;
#pragma unroll
        for (int rt = 0; rt < 2; rt++) {
            f32x4 acc[2][4] = {};
#pragma unroll
            for (int ks = 0; ks < 8; ks++) {
                short8 a0 = frag_read(As, rt * 32 + colq, ks, rq);
                short8 a1 = frag_read(As, rt * 32 + 16 + colq, ks, rq);
#pragma unroll
                for (int nf = 0; nf < 4; nf++) {
                    acc[0][nf] = __builtin_amdgcn_mfma_f32_16x16x32_bf16(a0, breg[nf][ks], acc[0][nf], 0, 0, 0);
                    acc[1][nf] = __builtin_amdgcn_mfma_f32_16x16x32_bf16(a1, breg[nf][ks], acc[1][nf], 0, 0, 0);
                }
            }
            // epilogue: acc -> rotated wave-private LDS, then coalesced stores
            char* epb = (char*)&ep[w][0];
            int rot = rq * 32;     // ((row>>2)&3)*32 == rq*32 for both mi
#pragma unroll
            for (int mi = 0; mi < 2; mi++)
#pragma unroll
                for (int r = 0; r < 4; r++) {
                    int row = mi * 16 + rq * 4 + r;
#pragma unroll
                    for (int nf = 0; nf < 4; nf++)
                        *(ushort_t*)(epb + row * 128 + ((nf * 32 + colq * 2 + rot) & 127)) =
                            f2bf(acc[mi][nf][r] + bv[nf]);
                }
#pragma unroll
            for (int j = 0; j < 4; j++) {
                int idx = j * 64 + lane;
                int rl = idx >> 3, cb8 = idx & 7;
                int grow = rc * 64 + rt * 32 + rl;
                if (grow < M)
                    *(uint4*)(C + (size_t)grow * HDIM + cg * 256 + w * 64 + cb8 * 8) =
                        *(const uint4*)(epb + rl * 128 + ((cb8 * 16 + ((rl >> 2) & 3) * 32) & 127));
            }
        }
    }
}

// ---------------------------------------------------------------------------
// P1 (fused x2): per-node attention scalars. grid = (1024, 2); grid-stride
// over 12500 wave-groups; weff LDS staged once per block.
// ---------------------------------------------------------------------------
__global__ void attn_all_kernel(const void* __restrict__ xu, const void* __restrict__ xi,
                                const float* __restrict__ weffu, const float* __restrict__ weffi,
                                const float* __restrict__ beffu, const float* __restrict__ beffi,
                                float* __restrict__ aqu, float* __restrict__ aku,
                                float* __restrict__ aqi, float* __restrict__ aki,
                                const int* __restrict__ flag) {
    const void* X = blockIdx.y ? xi : xu;
    const float* weff = blockIdx.y ? weffi : weffu;
    const float* beff = blockIdx.y ? beffi : beffu;
    float* aq = blockIdx.y ? aqi : aqu;
    float* ak = blockIdx.y ? aki : aku;
    __shared__ float wl[16 * KIN];
    int tid = threadIdx.x;
    for (int i = tid; i < 16 * KIN; i += 256) wl[i] = weff[i];
    bool fp32 = (*flag != 0);
    __syncthreads();
    int lane = tid & 63, w = tid >> 6;
    for (int g = blockIdx.x; g < 12500; g += 1024) {
        int n = g * 4 + w;
        float xv0, xv1, xv2, xv3;
        if (fp32) {
            const float* xr = (const float*)X + (size_t)n * KIN + lane * 4;
            float4 u = *(const float4*)xr;
            xv0 = u.x; xv1 = u.y; xv2 = u.z; xv3 = u.w;
        } else {
            const ushort_t* xr = (const ushort_t*)X + (size_t)n * KIN + lane * 4;
            uint2 u = *(const uint2*)xr;
            xv0 = bf2f(u.x & 0xffff); xv1 = bf2f(u.x >> 16);
            xv2 = bf2f(u.y & 0xffff); xv3 = bf2f(u.y >> 16);
        }
        float p[16];
#pragma unroll
        for (int o = 0; o < 16; o++) {
            float4 wv = *(const float4*)&wl[o * KIN + lane * 4];
            p[o] = xv0 * wv.x + xv1 * wv.y + xv2 * wv.z + xv3 * wv.w;
        }
#pragma unroll
        for (int o = 0; o < 16; o++) {
            float v = p[o];
#pragma unroll
            for (int m = 32; m > 0; m >>= 1) v += __shfl_xor(v, m);
            if (lane == o) {
                float r = v + beff[o];
                if (o < 8) aq[n * 8 + o] = r;
                else       ak[n * 8 + (o - 8)] = r;
            }
        }
    }
}

// ---------------------------------------------------------------------------
// E1 (fused x3): per-edge exp weights + denominator + degree. grid=(391,3)
// ---------------------------------------------------------------------------
__global__ void edge_pass1_all_kernel(
        const int* __restrict__ s0, const int* __restrict__ d0,
        const float* __restrict__ ak0, const float* __restrict__ aq0,
        float* __restrict__ w0, float* __restrict__ den_0, int* __restrict__ deg_0,
        const int* __restrict__ s1, const int* __restrict__ d1,
        const float* __restrict__ ak1, const float* __restrict__ aq1,
        float* __restrict__ w1, float* __restrict__ den_1, int* __restrict__ deg_1,
        const int* __restrict__ s2, const int* __restrict__ d2,
        const float* __restrict__ ak2, const float* __restrict__ aq2,
        float* __restrict__ w2, float* __restrict__ den_2, int* __restrict__ deg_2) {
    int y = blockIdx.y;
    const int* src = (y == 0) ? s0 : (y == 1) ? s1 : s2;
    const int* dst = (y == 0) ? d0 : (y == 1) ? d1 : d2;
    const float* ak = (y == 0) ? ak0 : (y == 1) ? ak1 : ak2;
    const float* aq = (y == 0) ? aq0 : (y == 1) ? aq1 : aq2;
    float* wbuf = (y == 0) ? w0 : (y == 1) ? w1 : w2;
    float* den  = (y == 0) ? den_0 : (y == 1) ? den_1 : den_2;
    int* deg    = (y == 0) ? deg_0 : (y == 1) ? deg_1 : deg_2;
    int e = blockIdx.x * 256 + threadIdx.x;
    if (e >= NEDGE) return;
    int s = src[e], d = dst[e];
#pragma unroll
    for (int h = 0; h < 8; h++) {
        float sc = ak[s * 8 + h] + aq[d * 8 + h];
        float wv = __expf(sc);
        wbuf[e * 8 + h] = wv;
        atomicAdd(&den[d * 8 + h], wv);
    }
    atomicAdd(&deg[d], 1);
}

// ---------------------------------------------------------------------------
// Scan: exclusive prefix sum of deg -> offs, 3 edge types, one launch
// ---------------------------------------------------------------------------
__global__ void scan3_kernel(const int* __restrict__ deg0, const int* __restrict__ deg1,
                             const int* __restrict__ deg2, int* __restrict__ offs0,
                             int* __restrict__ offs1, int* __restrict__ offs2) {
    const int Nd = NUSER;
    const int* deg = blockIdx.x == 0 ? deg0 : (blockIdx.x == 1 ? deg1 : deg2);
    int* offs = blockIdx.x == 0 ? offs0 : (blockIdx.x == 1 ? offs1 : offs2);
    __shared__ int lds[1024];
    int tid = threadIdx.x;
    int chunk = (Nd + 1023) >> 10;
    int s = tid * chunk;
    int e = s + chunk; if (e > Nd) e = Nd;
    int local = 0;
    for (int i = s; i < e; i++) local += deg[i];
    lds[tid] = local;
    __syncthreads();
    for (int d = 1; d < 1024; d <<= 1) {
        int v = (tid >= d) ? lds[tid - d] : 0;
        __syncthreads();
        lds[tid] += v;
        __syncthreads();
    }
    int run = (tid > 0) ? lds[tid - 1] : 0;
    for (int i = s; i < e; i++) { offs[i] = run; run += deg[i]; }
}

// ---------------------------------------------------------------------------
// E2 (fused x3): scatter edge ids into dst-sorted order. grid=(391,3)
// ---------------------------------------------------------------------------
__global__ void edge_scatter_all_kernel(
        const int* __restrict__ d0, const int* __restrict__ o0,
        int* __restrict__ c0, int* __restrict__ e0,
        const int* __restrict__ d1, const int* __restrict__ o1,
        int* __restrict__ c1, int* __restrict__ e1,
        const int* __restrict__ d2, const int* __restrict__ o2,
        int* __restrict__ c2, int* __restrict__ e2) {
    int y = blockIdx.y;
    const int* dst = (y == 0) ? d0 : (y == 1) ? d1 : d2;
    const int* offs = (y == 0) ? o0 : (y == 1) ? o1 : o2;
    int* cur = (y == 0) ? c0 : (y == 1) ? c1 : c2;
    int* esort = (y == 0) ? e0 : (y == 1) ? e1 : e2;
    int e = blockIdx.x * 256 + threadIdx.x;
    if (e >= NEDGE) return;
    int d = dst[e];
    int p = offs[d] + atomicAdd(&cur[d], 1);
    esort[p] = e;
}

// ---------------------------------------------------------------------------
// E3 helper: one wave aggregates one dst row for one etype.
// ---------------------------------------------------------------------------
static __device__ __forceinline__ void wave_agg_etype(
        int d, int lane, int hh,
        const int* __restrict__ src, const int* __restrict__ es,
        const int* __restrict__ offs, const int* __restrict__ deg,
        const float* __restrict__ den, const float* __restrict__ wbuf,
        const ushort_t* __restrict__ V, float* acc /*[8]*/, int* dg_out) {
    int dg = deg[d];
    int o0 = offs[d];
    *dg_out = dg;
    for (int base = 0; base < dg; base += 64) {
        int idx = base + lane;
        int ci = idx < dg ? idx : dg - 1;
        int el = es[o0 + ci];     // coalesced 64-wide prefetch
        int sl = src[el];
        int kmax = dg - base; if (kmax > 64) kmax = 64;
        for (int k = 0; k < kmax; k++) {
            int e = __shfl(el, k);
            int s = __shfl(sl, k);
            float wv = wbuf[e * 8 + hh];
            uint4 vv = *(const uint4*)(V + (size_t)s * HDIM + lane * 8);
            acc[0] += bf2f(vv.x & 0xffff) * wv;
            acc[1] += bf2f(vv.x >> 16) * wv;
            acc[2] += bf2f(vv.y & 0xffff) * wv;
            acc[3] += bf2f(vv.y >> 16) * wv;
            acc[4] += bf2f(vv.z & 0xffff) * wv;
            acc[5] += bf2f(vv.z >> 16) * wv;
            acc[6] += bf2f(vv.w & 0xffff) * wv;
            acc[7] += bf2f(vv.w >> 16) * wv;
        }
    }
}

// ---------------------------------------------------------------------------
// E3 (fused item+user): grid-stride over 25000 wave-groups (2048 blocks).
// wid < 12500: item group (clicks, v_u). wid >= 12500: user group
// (clicked_by v_i + follows v_u).
// ---------------------------------------------------------------------------
__global__ void agg_all_kernel(
        const int* __restrict__ src0, const int* __restrict__ es0,
        const int* __restrict__ offs0, const int* __restrict__ deg0,
        const float* __restrict__ den0, const float* __restrict__ wb0,
        const ushort_t* __restrict__ V0,
        const int* __restrict__ src1, const int* __restrict__ es1,
        const int* __restrict__ offs1, const int* __restrict__ deg1,
        const float* __restrict__ den1, const float* __restrict__ wb1,
        const ushort_t* __restrict__ V1,
        const int* __restrict__ src2, const int* __restrict__ es2,
        const int* __restrict__ offs2, const int* __restrict__ deg2,
        const float* __restrict__ den2, const float* __restrict__ wb2,
        const ushort_t* __restrict__ V2,
        void* __restrict__ outv, const int* __restrict__ flag) {
    int lane = threadIdx.x & 63;
    int wv = threadIdx.x >> 6;
    int hh = lane >> 3;
    bool f32o = (*flag != 0);
    for (int wid = blockIdx.x; wid < 25000; wid += 2048) {
        if (wid < 12500) {
            int d = wid * 4 + wv;
            float acc[8] = {};
            int dg;
            wave_agg_etype(d, lane, hh, src0, es0, offs0, deg0, den0, wb0, V0, acc, &dg);
            float inv = dg > 0 ? 1.0f / (den0[d * 8 + hh] * (float)dg) : 0.f;
            size_t base = (size_t)NUSER * HDIM + (size_t)d * HDIM + lane * 8;
            if (f32o) {
                float* o = (float*)outv + base;
#pragma unroll
                for (int j = 0; j < 8; j++) o[j] = acc[j] * inv;
            } else {
                uint4 o;
                o.x = (unsigned)f2bf(acc[0] * inv) | ((unsigned)f2bf(acc[1] * inv) << 16);
                o.y = (unsigned)f2bf(acc[2] * inv) | ((unsigned)f2bf(acc[3] * inv) << 16);
                o.z = (unsigned)f2bf(acc[4] * inv) | ((unsigned)f2bf(acc[5] * inv) << 16);
                o.w = (unsigned)f2bf(acc[6] * inv) | ((unsigned)f2bf(acc[7] * inv) << 16);
                *(uint4*)((ushort_t*)outv + base) = o;
            }
        } else {
            int d = (wid - 12500) * 4 + wv;
            float acc1[8] = {}, acc2[8] = {};
            int dg1, dg2;
            wave_agg_etype(d, lane, hh, src1, es1, offs1, deg1, den1, wb1, V1, acc1, &dg1);
            wave_agg_etype(d, lane, hh, src2, es2, offs2, deg2, den2, wb2, V2, acc2, &dg2);
            float inv1 = dg1 > 0 ? 1.0f / (den1[d * 8 + hh] * (float)dg1) : 0.f;
            float inv2 = dg2 > 0 ? 1.0f / (den2[d * 8 + hh] * (float)dg2) : 0.f;
            float r[8];
#pragma unroll
            for (int j = 0; j < 8; j++) r[j] = acc1[j] * inv1 + acc2[j] * inv2;
            size_t base = (size_t)d * HDIM + lane * 8;
            if (f32o) {
                float* o = (float*)outv + base;
#pragma unroll
                for (int j = 0; j < 8; j++) o[j] = r[j];
            } else {
                uint4 o;
                o.x = (unsigned)f2bf(r[0]) | ((unsigned)f2bf(r[1]) << 16);
                o.y = (unsigned)f2bf(r[2]) | ((unsigned)f2bf(r[3]) << 16);
                o.z = (unsigned)f2bf(r[4]) | ((unsigned)f2bf(r[5]) << 16);
                o.w = (unsigned)f2bf(r[6]) | ((unsigned)f2bf(r[7]) << 16);
                *(uint4*)((ushort_t*)outv + base) = o;
            }
        }
    }
}

// ---------------------------------------------------------------------------
// kernel_launch — 9 dispatches total
// ---------------------------------------------------------------------------
extern "C" void kernel_launch(void* const* d_in, const int* in_sizes, int n_in,
                              void* d_out, int out_size, void* d_ws, size_t ws_size,
                              hipStream_t stream) {
    const void* x_user  = d_in[0];
    const void* x_item  = d_in[1];
    const void* Wq_user = d_in[2];
    const void* bq_user = d_in[3];
    const void* Wk_user = d_in[4];
    const void* bk_user = d_in[5];
    const void* Wv_user = d_in[6];
    const void* bv_user = d_in[7];
    const void* Wq_item = d_in[8];
    const void* bq_item = d_in[9];
    const void* Wk_item = d_in[10];
    const void* bk_item = d_in[11];
    const void* Wv_item = d_in[12];
    const void* bv_item = d_in[13];
    const void* wa_user = d_in[14];
    const void* wa_item = d_in[15];
    const int* src_clicks     = (const int*)d_in[16];
    const int* dst_clicks     = (const int*)d_in[17];
    const int* src_clicked_by = (const int*)d_in[18];
    const int* dst_clicked_by = (const int*)d_in[19];
    const int* src_follows    = (const int*)d_in[20];
    const int* dst_follows    = (const int*)d_in[21];

    // workspace layout (bytes)
    char* ws = (char*)d_ws;
    ushort_t* v_u  = (ushort_t*)(ws + 0);           // 51,200,000
    ushort_t* v_i  = (ushort_t*)(ws + 51200000);    // 51,200,000
    float* aq_u    = (float*)(ws + 102400000);      // 1,600,000 each
    float* ak_u    = (float*)(ws + 104000000);
    float* aq_i    = (float*)(ws + 105600000);
    float* ak_i    = (float*)(ws + 107200000);
    float* weff_u  = (float*)(ws + 108800000);      // 16 KB (q rows 0-7, k rows 8-15)
    float* weff_i  = (float*)(ws + 108816384);      // 16 KB
    float* beff_u  = (float*)(ws + 108832768);      // 64 B (16 floats)
    float* beff_i  = (float*)(ws + 108832832);      // 64 B
    int*   dflag   = (int*)(ws + 108832896);        // 64 B (dtype flag)
    const size_t Z = 108832960;                     // zero-init region start
    float* den0 = (float*)(ws + Z + 0);             // 1,600,000 each
    float* den1 = (float*)(ws + Z + 1600000);
    float* den2 = (float*)(ws + Z + 3200000);
    int* deg0   = (int*)(ws + Z + 4800000);         // 200,000 each
    int* deg1   = (int*)(ws + Z + 5000000);
    int* deg2   = (int*)(ws + Z + 5200000);
    int* cur0   = (int*)(ws + Z + 5400000);
    int* cur1   = (int*)(ws + Z + 5600000);
    int* cur2   = (int*)(ws + Z + 5800000);
    const size_t ZLEN = 6000000;
    int* offs0  = (int*)(ws + Z + 6000000);
    int* offs1  = (int*)(ws + Z + 6200000);
    int* offs2  = (int*)(ws + Z + 6400000);
    int* es0    = (int*)(ws + Z + 6600000);         // 400,000 each
    int* es1    = (int*)(ws + Z + 7000000);
    int* es2    = (int*)(ws + Z + 7400000);
    float* wb0  = (float*)(ws + Z + 7800000);       // 3,200,000 each
    float* wb1  = (float*)(ws + Z + 11000000);
    float* wb2  = (float*)(ws + Z + 14200000);
    if (ws_size < Z + 17400000) return;

    // D0: dtype detect (must run first; consumers branch on dflag)
    detect_kernel<<<1, 256, 0, stream>>>((const ushort_t*)x_user, dflag);

    // zero-init atomic accumulators (den/deg/cur)
    hipMemsetAsync(ws + Z, 0, ZLEN, stream);

    // P0: all four effective-weight projections in one launch
    eff_w_all_kernel<<<dim3(8, 4), 256, 0, stream>>>(
        Wq_user, bq_user, Wk_user, bk_user, Wq_item, bq_item, Wk_item, bk_item,
        wa_user, wa_item, weff_u, weff_i, beff_u, beff_i, dflag);

    // P2: both v projections, one launch
    gemm_v5_kernel<<<dim3(512, 2), 256, 0, stream>>>(
        x_user, Wv_user, bv_user, v_u, x_item, Wv_item, bv_item, v_i, NUSER, dflag);

    // P1: both attention-scalar passes, one launch (grid-stride)
    attn_all_kernel<<<dim3(1024, 2), 256, 0, stream>>>(
        x_user, x_item, weff_u, weff_i, beff_u, beff_i,
        aq_u, ak_u, aq_i, ak_i, dflag);

    // E1: all three edge types, one launch
    edge_pass1_all_kernel<<<dim3(391, 3), 256, 0, stream>>>(
        src_clicks, dst_clicks, ak_u, aq_i, wb0, den0, deg0,
        src_clicked_by, dst_clicked_by, ak_i, aq_u, wb1, den1, deg1,
        src_follows, dst_follows, ak_u, aq_u, wb2, den2, deg2);

    // scan (all 3 etypes, one launch)
    scan3_kernel<<<3, 1024, 0, stream>>>(deg0, deg1, deg2, offs0, offs1, offs2);

    // E2: all three scatters, one launch
    edge_scatter_all_kernel<<<dim3(391, 3), 256, 0, stream>>>(
        dst_clicks, offs0, cur0, es0,
        dst_clicked_by, offs1, cur1, es1,
        dst_follows, offs2, cur2, es2);

    // E3: item + user aggregation, one launch (grid-stride)
    agg_all_kernel<<<2048, 256, 0, stream>>>(
        src_clicks, es0, offs0, deg0, den0, wb0, v_u,
        src_clicked_by, es1, offs1, deg1, den1, wb1, v_i,
        src_follows, es2, offs2, deg2, den2, wb2, v_u,
        d_out, dflag);
}

// Round 7
// 702.063 us; speedup vs baseline: 1.5433x; 1.1914x over previous
//
#include <hip/hip_runtime.h>

// ---------------------------------------------------------------------------
// Problem constants
// ---------------------------------------------------------------------------
#define NUSER 50000
#define NITEM 50000
#define NEDGE 100000
#define HDIM  512      // H*D
#define KIN   256      // input feature dim

typedef unsigned short ushort_t;
typedef __attribute__((ext_vector_type(8))) short short8;
typedef __attribute__((ext_vector_type(4))) float f32x4;

static __device__ __forceinline__ float bf2f(ushort_t u) {
    unsigned v = ((unsigned)u) << 16;
    float f;
    __builtin_memcpy(&f, &v, 4);
    return f;
}
static __device__ __forceinline__ ushort_t f2bf(float f) {
    unsigned u;
    __builtin_memcpy(&u, &f, 4);
    unsigned r = u + 0x7fffu + ((u >> 16) & 1u);  // RNE
    return (ushort_t)(r >> 16);
}
// runtime-dtype scalar load
static __device__ __forceinline__ float ldf(const void* p, long i, bool fp32) {
    return fp32 ? ((const float*)p)[i] : bf2f(((const ushort_t*)p)[i]);
}

// ---------------------------------------------------------------------------
// D0: runtime dtype detection (0 = bf16, 1 = fp32)
// ---------------------------------------------------------------------------
__global__ void detect_kernel(const ushort_t* __restrict__ x, int* __restrict__ flag) {
    __shared__ float red[256];
    int tid = threadIdx.x;
    float m = 0.f;
    for (int i = tid; i < 4096; i += 256) m = fmaxf(m, fabsf(bf2f(x[i])));
    red[tid] = m;
    __syncthreads();
    for (int s = 128; s > 0; s >>= 1) {
        if (tid < s) red[tid] = fmaxf(red[tid], red[tid + s]);
        __syncthreads();
    }
    if (tid == 0) *flag = (red[0] > 1e6f) ? 1 : 0;
}

// ---------------------------------------------------------------------------
// P0 (fused x4): effective attention weights. grid = (8 heads, 4 targets).
// y: 0=q_user 1=k_user 2=q_item 3=k_item
// ---------------------------------------------------------------------------
__global__ void eff_w_all_kernel(
        const void* __restrict__ Wqu, const void* __restrict__ bqu,
        const void* __restrict__ Wku, const void* __restrict__ bku,
        const void* __restrict__ Wqi, const void* __restrict__ bqi,
        const void* __restrict__ Wki, const void* __restrict__ bki,
        const void* __restrict__ wau, const void* __restrict__ wai,
        float* __restrict__ weffu, float* __restrict__ weffi,
        float* __restrict__ beffu, float* __restrict__ beffi,
        const int* __restrict__ flag) {
    int y = blockIdx.y;
    const void* W  = (y == 0) ? Wqu : (y == 1) ? Wku : (y == 2) ? Wqi : Wki;
    const void* b  = (y == 0) ? bqu : (y == 1) ? bku : (y == 2) ? bqi : bki;
    const void* wa = (y < 2) ? wau : wai;
    float* weff = ((y < 2) ? weffu : weffi) + (y & 1) * 2048;
    float* beff = ((y < 2) ? beffu : beffi) + (y & 1) * 8;
    bool fp32 = (*flag != 0);
    int h = blockIdx.x;      // 0..7
    int k = threadIdx.x;     // 0..255
    __shared__ float was[64];
    __shared__ float red[64];
    if (k < 64) was[k] = ldf(wa, k, fp32);
    __syncthreads();
    float s = 0.f;
#pragma unroll 8
    for (int d = 0; d < 64; d++)
        s += was[d] * ldf(W, (long)(h * 64 + d) * KIN + k, fp32);
    weff[h * KIN + k] = 0.125f * s;
    if (k < 64) red[k] = was[k] * ldf(b, h * 64 + k, fp32);
    __syncthreads();
    if (k == 0) {
        float t = 0.f;
        for (int d = 0; d < 64; d++) t += red[d];
        beff[h] = 0.125f * t;
    }
}

// ---------------------------------------------------------------------------
// GEMM v5 helpers: coalesced staging into rotation-swizzled row-major LDS.
// ---------------------------------------------------------------------------
static __device__ __forceinline__ void stage_tile_fp32(
        const float* __restrict__ G, ushort_t* lds, int base_row, int maxrow, int tid) {
    int lane = tid & 63, w = tid >> 6;
#pragma unroll
    for (int i = 0; i < 16; i++) {
        int row_l = i * 4 + w;                       // one full row per wave-instr
        int grow = base_row + row_l; if (grow > maxrow) grow = maxrow;
        float4 v = *(const float4*)(G + (size_t)grow * KIN + lane * 4);
        uint2 u;
        u.x = (unsigned)f2bf(v.x) | ((unsigned)f2bf(v.y) << 16);
        u.y = (unsigned)f2bf(v.z) | ((unsigned)f2bf(v.w) << 16);
        int byte = row_l * 512 + ((lane * 8 + ((row_l & 7) << 6)) & 511);
        *(uint2*)((char*)lds + byte) = u;
    }
}
static __device__ __forceinline__ void stage_tile_bf16(
        const ushort_t* __restrict__ G, ushort_t* lds, int base_row, int maxrow, int tid) {
#pragma unroll
    for (int i = 0; i < 8; i++) {
        int chunk = i * 256 + tid;                   // 16B chunks, 32 per row
        int row_l = chunk >> 5, hw = chunk & 31;
        int grow = base_row + row_l; if (grow > maxrow) grow = maxrow;
        uint4 v = *(const uint4*)(G + (size_t)grow * KIN + hw * 8);
        int byte = row_l * 512 + ((hw * 16 + ((row_l & 7) << 6)) & 511);
        *(uint4*)((char*)lds + byte) = v;
    }
}
// fragment read: lane (colq,rq) gets k = ks*32 + rq*8 .. +7 of row_l
static __device__ __forceinline__ short8 frag_read(const ushort_t* lds, int row_l,
                                                   int ks, int rq) {
    int byte = row_l * 512 + (((ks * 64 + rq * 16) + ((row_l & 7) << 6)) & 511);
    return *(const short8*)((const char*)lds + byte);
}

// ---------------------------------------------------------------------------
// P2 (fused x2): v projection GEMM v5. grid = (512, 2); y selects user/item.
// ---------------------------------------------------------------------------
__global__ __launch_bounds__(256, 2) void gemm_v5_kernel(
        const void* __restrict__ Au, const void* __restrict__ Wu,
        const void* __restrict__ bu, ushort_t* __restrict__ Cu,
        const void* __restrict__ Ai, const void* __restrict__ Wi,
        const void* __restrict__ bi, ushort_t* __restrict__ Ci,
        int M, const int* __restrict__ flag) {
    __shared__ __align__(16) ushort_t As[64 * 256];   // 32 KB
    __shared__ __align__(16) ushort_t Bs[64 * 256];   // 32 KB
    __shared__ __align__(16) ushort_t ep[4][2048];    // 16 KB
    const void* A    = blockIdx.y ? Ai : Au;
    const void* W    = blockIdx.y ? Wi : Wu;
    const void* bias = blockIdx.y ? bi : bu;
    ushort_t* C      = blockIdx.y ? Ci : Cu;
    bool fp32 = (*flag != 0);
    int tid = threadIdx.x, lane = tid & 63, w = tid >> 6;
    int b = blockIdx.x, cg = b & 1, rc0 = b >> 1;
    int colq = lane & 15, rq = lane >> 4;
    int nf0 = cg * 16 + w * 4;

    // first A tile staged early; completes under the B-quarter barriers
    if (fp32) stage_tile_fp32((const float*)A, As, rc0 * 64, M - 1, tid);
    else      stage_tile_bf16((const ushort_t*)A, As, rc0 * 64, M - 1, tid);

    // B: W strip quarter-by-quarter through Bs; wave q keeps quarter q in regs
    short8 breg[4][8];
#pragma unroll
    for (int q = 0; q < 4; q++) {
        if (fp32) stage_tile_fp32((const float*)W, Bs, cg * 256 + q * 64, 511, tid);
        else      stage_tile_bf16((const ushort_t*)W, Bs, cg * 256 + q * 64, 511, tid);
        __syncthreads();
        if (w == q) {
#pragma unroll
            for (int nf = 0; nf < 4; nf++)
#pragma unroll
                for (int ks = 0; ks < 8; ks++)
                    breg[nf][ks] = frag_read(Bs, nf * 16 + colq, ks, rq);
        }
        __syncthreads();
    }
    float bv[4];
#pragma unroll
    for (int nf = 0; nf < 4; nf++)
        bv[nf] = ldf(bias, (nf0 + nf) * 16 + colq, fp32);

    bool first = true;
    for (int rc = rc0; rc < 782; rc += 256) {
        if (!first) {
            __syncthreads();       // prior iter's frag reads done
            if (fp32) stage_tile_fp32((const float*)A, As, rc * 64, M - 1, tid);
            else      stage_tile_bf16((const ushort_t*)A, As, rc * 64, M - 1, tid);
            __syncthreads();
        }
        first = false;
#pragma unroll
        for (int rt = 0; rt < 2; rt++) {
            f32x4 acc[2][4] = {};
#pragma unroll
            for (int ks = 0; ks < 8; ks++) {
                short8 a0 = frag_read(As, rt * 32 + colq, ks, rq);
                short8 a1 = frag_read(As, rt * 32 + 16 + colq, ks, rq);
#pragma unroll
                for (int nf = 0; nf < 4; nf++) {
                    acc[0][nf] = __builtin_amdgcn_mfma_f32_16x16x32_bf16(a0, breg[nf][ks], acc[0][nf], 0, 0, 0);
                    acc[1][nf] = __builtin_amdgcn_mfma_f32_16x16x32_bf16(a1, breg[nf][ks], acc[1][nf], 0, 0, 0);
                }
            }
            // epilogue: acc -> rotated wave-private LDS, then coalesced stores
            char* epb = (char*)&ep[w][0];
            int rot = rq * 32;
#pragma unroll
            for (int mi = 0; mi < 2; mi++)
#pragma unroll
                for (int r = 0; r < 4; r++) {
                    int row = mi * 16 + rq * 4 + r;
#pragma unroll
                    for (int nf = 0; nf < 4; nf++)
                        *(ushort_t*)(epb + row * 128 + ((nf * 32 + colq * 2 + rot) & 127)) =
                            f2bf(acc[mi][nf][r] + bv[nf]);
                }
#pragma unroll
            for (int j = 0; j < 4; j++) {
                int idx = j * 64 + lane;
                int rl = idx >> 3, cb8 = idx & 7;
                int grow = rc * 64 + rt * 32 + rl;
                if (grow < M)
                    *(uint4*)(C + (size_t)grow * HDIM + cg * 256 + w * 64 + cb8 * 8) =
                        *(const uint4*)(epb + rl * 128 + ((cb8 * 16 + ((rl >> 2) & 3) * 32) & 127));
            }
        }
    }
}

// ---------------------------------------------------------------------------
// P1 (fused x2): per-node attention scalars. grid = (1024, 2)
// ---------------------------------------------------------------------------
__global__ void attn_all_kernel(const void* __restrict__ xu, const void* __restrict__ xi,
                                const float* __restrict__ weffu, const float* __restrict__ weffi,
                                const float* __restrict__ beffu, const float* __restrict__ beffi,
                                float* __restrict__ aqu, float* __restrict__ aku,
                                float* __restrict__ aqi, float* __restrict__ aki,
                                const int* __restrict__ flag) {
    const void* X = blockIdx.y ? xi : xu;
    const float* weff = blockIdx.y ? weffi : weffu;
    const float* beff = blockIdx.y ? beffi : beffu;
    float* aq = blockIdx.y ? aqi : aqu;
    float* ak = blockIdx.y ? aki : aku;
    __shared__ float wl[16 * KIN];
    int tid = threadIdx.x;
    for (int i = tid; i < 16 * KIN; i += 256) wl[i] = weff[i];
    bool fp32 = (*flag != 0);
    __syncthreads();
    int lane = tid & 63, w = tid >> 6;
    for (int g = blockIdx.x; g < 12500; g += 1024) {
        int n = g * 4 + w;
        float xv0, xv1, xv2, xv3;
        if (fp32) {
            const float* xr = (const float*)X + (size_t)n * KIN + lane * 4;
            float4 u = *(const float4*)xr;
            xv0 = u.x; xv1 = u.y; xv2 = u.z; xv3 = u.w;
        } else {
            const ushort_t* xr = (const ushort_t*)X + (size_t)n * KIN + lane * 4;
            uint2 u = *(const uint2*)xr;
            xv0 = bf2f(u.x & 0xffff); xv1 = bf2f(u.x >> 16);
            xv2 = bf2f(u.y & 0xffff); xv3 = bf2f(u.y >> 16);
        }
        float p[16];
#pragma unroll
        for (int o = 0; o < 16; o++) {
            float4 wv = *(const float4*)&wl[o * KIN + lane * 4];
            p[o] = xv0 * wv.x + xv1 * wv.y + xv2 * wv.z + xv3 * wv.w;
        }
#pragma unroll
        for (int o = 0; o < 16; o++) {
            float v = p[o];
#pragma unroll
            for (int m = 32; m > 0; m >>= 1) v += __shfl_xor(v, m);
            if (lane == o) {
                float r = v + beff[o];
                if (o < 8) aq[n * 8 + o] = r;
                else       ak[n * 8 + (o - 8)] = r;
            }
        }
    }
}

// ---------------------------------------------------------------------------
// E1 (lightweight): degree count only, all 3 etypes. grid = (391, 3).
// den/wbuf are gone: exp-weights and denominators are computed in-register
// inside the aggregation waves (deterministic per-wave order).
// ---------------------------------------------------------------------------
__global__ void deg_count_all_kernel(
        const int* __restrict__ d0, int* __restrict__ deg_0,
        const int* __restrict__ d1, int* __restrict__ deg_1,
        const int* __restrict__ d2, int* __restrict__ deg_2) {
    int y = blockIdx.y;
    const int* dst = (y == 0) ? d0 : (y == 1) ? d1 : d2;
    int* deg       = (y == 0) ? deg_0 : (y == 1) ? deg_1 : deg_2;
    int e = blockIdx.x * 256 + threadIdx.x;
    if (e >= NEDGE) return;
    atomicAdd(&deg[dst[e]], 1);
}

// ---------------------------------------------------------------------------
// Scan: exclusive prefix sum of deg -> offs, 3 edge types, one launch
// ---------------------------------------------------------------------------
__global__ void scan3_kernel(const int* __restrict__ deg0, const int* __restrict__ deg1,
                             const int* __restrict__ deg2, int* __restrict__ offs0,
                             int* __restrict__ offs1, int* __restrict__ offs2) {
    const int Nd = NUSER;
    const int* deg = blockIdx.x == 0 ? deg0 : (blockIdx.x == 1 ? deg1 : deg2);
    int* offs = blockIdx.x == 0 ? offs0 : (blockIdx.x == 1 ? offs1 : offs2);
    __shared__ int lds[1024];
    int tid = threadIdx.x;
    int chunk = (Nd + 1023) >> 10;
    int s = tid * chunk;
    int e = s + chunk; if (e > Nd) e = Nd;
    int local = 0;
    for (int i = s; i < e; i++) local += deg[i];
    lds[tid] = local;
    __syncthreads();
    for (int d = 1; d < 1024; d <<= 1) {
        int v = (tid >= d) ? lds[tid - d] : 0;
        __syncthreads();
        lds[tid] += v;
        __syncthreads();
    }
    int run = (tid > 0) ? lds[tid - 1] : 0;
    for (int i = s; i < e; i++) { offs[i] = run; run += deg[i]; }
}

// ---------------------------------------------------------------------------
// E2 (fused x3): scatter edge ids into dst-sorted order. grid=(391,3)
// ---------------------------------------------------------------------------
__global__ void edge_scatter_all_kernel(
        const int* __restrict__ d0, const int* __restrict__ o0,
        int* __restrict__ c0, int* __restrict__ e0,
        const int* __restrict__ d1, const int* __restrict__ o1,
        int* __restrict__ c1, int* __restrict__ e1,
        const int* __restrict__ d2, const int* __restrict__ o2,
        int* __restrict__ c2, int* __restrict__ e2) {
    int y = blockIdx.y;
    const int* dst = (y == 0) ? d0 : (y == 1) ? d1 : d2;
    const int* offs = (y == 0) ? o0 : (y == 1) ? o1 : o2;
    int* cur = (y == 0) ? c0 : (y == 1) ? c1 : c2;
    int* esort = (y == 0) ? e0 : (y == 1) ? e1 : e2;
    int e = blockIdx.x * 256 + threadIdx.x;
    if (e >= NEDGE) return;
    int d = dst[e];
    int p = offs[d] + atomicAdd(&cur[d], 1);
    esort[p] = e;
}

// ---------------------------------------------------------------------------
// E3 helper: one wave aggregates one dst row for one etype.
// Edge softmax weights computed in-register: wv = exp(ak[src][hh] + aq[d][hh])
// (aq loaded once per wave; ak is a 32B broadcast line per edge, same traffic
// as the old wbuf read). den accumulated in-register — no atomics, no wbuf.
// ---------------------------------------------------------------------------
static __device__ __forceinline__ void wave_agg_etype(
        int d, int lane, int hh,
        const int* __restrict__ src, const int* __restrict__ es,
        const int* __restrict__ offs, const int* __restrict__ deg,
        const float* __restrict__ ak, const float* __restrict__ aq,
        const ushort_t* __restrict__ V, float* acc /*[8]*/,
        float* den_out, int* dg_out) {
    int dg = deg[d];
    int o0 = offs[d];
    *dg_out = dg;
    float aqv = aq[d * 8 + hh];
    float den = 0.f;
    for (int base = 0; base < dg; base += 64) {
        int idx = base + lane;
        int ci = idx < dg ? idx : dg - 1;
        int el = es[o0 + ci];     // coalesced 64-wide prefetch
        int sl = src[el];
        int kmax = dg - base; if (kmax > 64) kmax = 64;
        for (int k = 0; k < kmax; k++) {
            int s = __shfl(sl, k);
            float wv = __expf(ak[s * 8 + hh] + aqv);
            den += wv;
            uint4 vv = *(const uint4*)(V + (size_t)s * HDIM + lane * 8);
            acc[0] += bf2f(vv.x & 0xffff) * wv;
            acc[1] += bf2f(vv.x >> 16) * wv;
            acc[2] += bf2f(vv.y & 0xffff) * wv;
            acc[3] += bf2f(vv.y >> 16) * wv;
            acc[4] += bf2f(vv.z & 0xffff) * wv;
            acc[5] += bf2f(vv.z >> 16) * wv;
            acc[6] += bf2f(vv.w & 0xffff) * wv;
            acc[7] += bf2f(vv.w >> 16) * wv;
        }
    }
    *den_out = den;
}

// ---------------------------------------------------------------------------
// E3 (fused item+user): grid-stride over 25000 wave-groups (2048 blocks).
// ---------------------------------------------------------------------------
__global__ void agg_all_kernel(
        const int* __restrict__ src0, const int* __restrict__ es0,
        const int* __restrict__ offs0, const int* __restrict__ deg0,
        const ushort_t* __restrict__ V0,
        const int* __restrict__ src1, const int* __restrict__ es1,
        const int* __restrict__ offs1, const int* __restrict__ deg1,
        const ushort_t* __restrict__ V1,
        const int* __restrict__ src2, const int* __restrict__ es2,
        const int* __restrict__ offs2, const int* __restrict__ deg2,
        const ushort_t* __restrict__ V2,
        const float* __restrict__ aq_u, const float* __restrict__ ak_u,
        const float* __restrict__ aq_i, const float* __restrict__ ak_i,
        void* __restrict__ outv, const int* __restrict__ flag) {
    int lane = threadIdx.x & 63;
    int wv = threadIdx.x >> 6;
    int hh = lane >> 3;
    bool f32o = (*flag != 0);
    for (int wid = blockIdx.x; wid < 25000; wid += 2048) {
        if (wid < 12500) {
            // item dst: clicks (src=user): score = ak_u[src] + aq_i[dst]
            int d = wid * 4 + wv;
            float acc[8] = {};
            float den; int dg;
            wave_agg_etype(d, lane, hh, src0, es0, offs0, deg0, ak_u, aq_i, V0, acc, &den, &dg);
            float inv = dg > 0 ? 1.0f / (den * (float)dg) : 0.f;
            size_t base = (size_t)NUSER * HDIM + (size_t)d * HDIM + lane * 8;
            if (f32o) {
                float* o = (float*)outv + base;
#pragma unroll
                for (int j = 0; j < 8; j++) o[j] = acc[j] * inv;
            } else {
                uint4 o;
                o.x = (unsigned)f2bf(acc[0] * inv) | ((unsigned)f2bf(acc[1] * inv) << 16);
                o.y = (unsigned)f2bf(acc[2] * inv) | ((unsigned)f2bf(acc[3] * inv) << 16);
                o.z = (unsigned)f2bf(acc[4] * inv) | ((unsigned)f2bf(acc[5] * inv) << 16);
                o.w = (unsigned)f2bf(acc[6] * inv) | ((unsigned)f2bf(acc[7] * inv) << 16);
                *(uint4*)((ushort_t*)outv + base) = o;
            }
        } else {
            // user dst: clicked_by (src=item) + follows (src=user)
            int d = (wid - 12500) * 4 + wv;
            float acc1[8] = {}, acc2[8] = {};
            float den1, den2; int dg1, dg2;
            wave_agg_etype(d, lane, hh, src1, es1, offs1, deg1, ak_i, aq_u, V1, acc1, &den1, &dg1);
            wave_agg_etype(d, lane, hh, src2, es2, offs2, deg2, ak_u, aq_u, V2, acc2, &den2, &dg2);
            float inv1 = dg1 > 0 ? 1.0f / (den1 * (float)dg1) : 0.f;
            float inv2 = dg2 > 0 ? 1.0f / (den2 * (float)dg2) : 0.f;
            float r[8];
#pragma unroll
            for (int j = 0; j < 8; j++) r[j] = acc1[j] * inv1 + acc2[j] * inv2;
            size_t base = (size_t)d * HDIM + lane * 8;
            if (f32o) {
                float* o = (float*)outv + base;
#pragma unroll
                for (int j = 0; j < 8; j++) o[j] = r[j];
            } else {
                uint4 o;
                o.x = (unsigned)f2bf(r[0]) | ((unsigned)f2bf(r[1]) << 16);
                o.y = (unsigned)f2bf(r[2]) | ((unsigned)f2bf(r[3]) << 16);
                o.z = (unsigned)f2bf(r[4]) | ((unsigned)f2bf(r[5]) << 16);
                o.w = (unsigned)f2bf(r[6]) | ((unsigned)f2bf(r[7]) << 16);
                *(uint4*)((ushort_t*)outv + base) = o;
            }
        }
    }
}

// ---------------------------------------------------------------------------
// kernel_launch — 8 dispatches total
// ---------------------------------------------------------------------------
extern "C" void kernel_launch(void* const* d_in, const int* in_sizes, int n_in,
                              void* d_out, int out_size, void* d_ws, size_t ws_size,
                              hipStream_t stream) {
    const void* x_user  = d_in[0];
    const void* x_item  = d_in[1];
    const void* Wq_user = d_in[2];
    const void* bq_user = d_in[3];
    const void* Wk_user = d_in[4];
    const void* bk_user = d_in[5];
    const void* Wv_user = d_in[6];
    const void* bv_user = d_in[7];
    const void* Wq_item = d_in[8];
    const void* bq_item = d_in[9];
    const void* Wk_item = d_in[10];
    const void* bk_item = d_in[11];
    const void* Wv_item = d_in[12];
    const void* bv_item = d_in[13];
    const void* wa_user = d_in[14];
    const void* wa_item = d_in[15];
    const int* src_clicks     = (const int*)d_in[16];
    const int* dst_clicks     = (const int*)d_in[17];
    const int* src_clicked_by = (const int*)d_in[18];
    const int* dst_clicked_by = (const int*)d_in[19];
    const int* src_follows    = (const int*)d_in[20];
    const int* dst_follows    = (const int*)d_in[21];

    // workspace layout (bytes)
    char* ws = (char*)d_ws;
    ushort_t* v_u  = (ushort_t*)(ws + 0);           // 51,200,000
    ushort_t* v_i  = (ushort_t*)(ws + 51200000);    // 51,200,000
    float* aq_u    = (float*)(ws + 102400000);      // 1,600,000 each
    float* ak_u    = (float*)(ws + 104000000);
    float* aq_i    = (float*)(ws + 105600000);
    float* ak_i    = (float*)(ws + 107200000);
    float* weff_u  = (float*)(ws + 108800000);      // 16 KB (q rows 0-7, k rows 8-15)
    float* weff_i  = (float*)(ws + 108816384);      // 16 KB
    float* beff_u  = (float*)(ws + 108832768);      // 64 B (16 floats)
    float* beff_i  = (float*)(ws + 108832832);      // 64 B
    int*   dflag   = (int*)(ws + 108832896);        // 64 B (dtype flag)
    const size_t Z = 108832960;                     // zero-init region start
    // den0/1/2 slots retained in layout but unused (den now in-register)
    int* deg0   = (int*)(ws + Z + 4800000);         // 200,000 each
    int* deg1   = (int*)(ws + Z + 5000000);
    int* deg2   = (int*)(ws + Z + 5200000);
    int* cur0   = (int*)(ws + Z + 5400000);
    int* cur1   = (int*)(ws + Z + 5600000);
    int* cur2   = (int*)(ws + Z + 5800000);
    int* offs0  = (int*)(ws + Z + 6000000);
    int* offs1  = (int*)(ws + Z + 6200000);
    int* offs2  = (int*)(ws + Z + 6400000);
    int* es0    = (int*)(ws + Z + 6600000);         // 400,000 each
    int* es1    = (int*)(ws + Z + 7000000);
    int* es2    = (int*)(ws + Z + 7400000);
    if (ws_size < Z + 17400000) return;

    // D0: dtype detect (must run first; consumers branch on dflag)
    detect_kernel<<<1, 256, 0, stream>>>((const ushort_t*)x_user, dflag);

    // zero-init atomic counters (deg/cur only — 1.2 MB)
    hipMemsetAsync(ws + Z + 4800000, 0, 1200000, stream);

    // P0: all four effective-weight projections in one launch
    eff_w_all_kernel<<<dim3(8, 4), 256, 0, stream>>>(
        Wq_user, bq_user, Wk_user, bk_user, Wq_item, bq_item, Wk_item, bk_item,
        wa_user, wa_item, weff_u, weff_i, beff_u, beff_i, dflag);

    // P2: both v projections, one launch
    gemm_v5_kernel<<<dim3(512, 2), 256, 0, stream>>>(
        x_user, Wv_user, bv_user, v_u, x_item, Wv_item, bv_item, v_i, NUSER, dflag);

    // P1: both attention-scalar passes, one launch (grid-stride)
    attn_all_kernel<<<dim3(1024, 2), 256, 0, stream>>>(
        x_user, x_item, weff_u, weff_i, beff_u, beff_i,
        aq_u, ak_u, aq_i, ak_i, dflag);

    // E1: degree counts only (den/wbuf eliminated)
    deg_count_all_kernel<<<dim3(391, 3), 256, 0, stream>>>(
        dst_clicks, deg0, dst_clicked_by, deg1, dst_follows, deg2);

    // scan (all 3 etypes, one launch)
    scan3_kernel<<<3, 1024, 0, stream>>>(deg0, deg1, deg2, offs0, offs1, offs2);

    // E2: all three scatters, one launch
    edge_scatter_all_kernel<<<dim3(391, 3), 256, 0, stream>>>(
        dst_clicks, offs0, cur0, es0,
        dst_clicked_by, offs1, cur1, es1,
        dst_follows, offs2, cur2, es2);

    // E3: item + user aggregation, one launch (grid-stride); softmax weights
    // and denominators computed in-register
    agg_all_kernel<<<2048, 256, 0, stream>>>(
        src_clicks, es0, offs0, deg0, v_u,
        src_clicked_by, es1, offs1, deg1, v_i,
        src_follows, es2, offs2, deg2, v_u,
        aq_u, ak_u, aq_i, ak_i,
        d_out, dflag);
}